// Round 1
// baseline (596.743 us; speedup 1.0000x reference)
//
#include <hip/hip_runtime.h>
#include <hip/hip_bf16.h>

#define B_    1024
#define C_    512
#define H_    8
#define D_    64
#define QKVC_ 80
#define EPS_  1e-5f

typedef __attribute__((ext_vector_type(4))) float f32x4;
typedef __attribute__((ext_vector_type(8))) short bf16x8;
typedef __attribute__((ext_vector_type(8))) unsigned short u16x8;

__device__ __forceinline__ float bf2f(unsigned short h) {
    union { unsigned int u; float f; } c;
    c.u = ((unsigned int)h) << 16;
    return c.f;
}
__device__ __forceinline__ unsigned short f2bf(float f) {
    __hip_bfloat16 h = __float2bfloat16(f);
    return *reinterpret_cast<unsigned short*>(&h);
}

// ---------------------------------------------------------------------------
// K1: qkv[b,o,d] = BN1( sum_c conv_w[o,c] * x[b,c,d] )
// stored to ws as [b][h][c][d] with o = c*8 + h.
// bf16 MFMA 16x16x32, f32 accumulate. Block = 256 thr (4 waves).
// Each block: one b, 320 rows of o (2 blocks per b). Wave: 80 rows (5 frags).
// ---------------------------------------------------------------------------
#define MT  320
#define KT  32
#define LDW 40   // padded LDS row stride (bf16 elems): 80 B -> 2-way banks, 16B-aligned

__global__ __launch_bounds__(256) void k1_gemm(
    const float* __restrict__ x, const float* __restrict__ w,
    const float* __restrict__ g1, const float* __restrict__ b1,
    const float* __restrict__ m1, const float* __restrict__ v1,
    float* __restrict__ qkv)
{
    __shared__ unsigned short wt[MT * LDW];   // 25600 B
    __shared__ unsigned short xt[64 * LDW];   // 5120 B  (x transposed: xt[d][k])
    __shared__ float ssc[MT], ssh[MT];

    const int tid  = threadIdx.x;
    const int b    = blockIdx.x >> 1;
    const int row0 = (blockIdx.x & 1) * MT;

    for (int t = tid; t < MT; t += 256) {
        int o = row0 + t;
        float sc = g1[o] * rsqrtf(v1[o] + EPS_);
        ssc[t] = sc;
        ssh[t] = b1[o] - m1[o] * sc;
    }

    const int lane = tid & 63;
    const int wv   = tid >> 6;        // wave 0..3
    const int wrow = wv * 80;
    const int lm   = lane & 15;       // m (A) / n (B) index inside fragment
    const int lk   = (lane >> 4) * 8; // k offset inside fragment

    f32x4 acc[5][4];
#pragma unroll
    for (int i = 0; i < 5; ++i)
#pragma unroll
        for (int j = 0; j < 4; ++j) acc[i][j] = (f32x4){0.f, 0.f, 0.f, 0.f};

    const float* xb = x + (size_t)b * C_ * D_;

    for (int kk = 0; kk < C_; kk += KT) {
        __syncthreads();   // protect LDS from previous iteration's fragment reads
        // stage W tile (rows row0..row0+319, cols kk..kk+31) as bf16
#pragma unroll
        for (int it = 0; it < 20; ++it) {
            int idx = tid + it * 256;        // 0..5119 (f32 pairs)
            int r   = idx >> 4;              // 0..319
            int cp  = (idx & 15) * 2;        // 0,2,..,30
            const float2 a = *reinterpret_cast<const float2*>(
                w + (size_t)(row0 + r) * C_ + kk + cp);
            unsigned int pk = (unsigned int)f2bf(a.x) | ((unsigned int)f2bf(a.y) << 16);
            *reinterpret_cast<unsigned int*>(&wt[r * LDW + cp]) = pk;
        }
        // stage X tile transposed: xt[d][k]
#pragma unroll
        for (int it = 0; it < 8; ++it) {
            int idx = tid + it * 256;        // 0..2047
            int k   = idx >> 6;              // 0..31
            int d   = idx & 63;
            xt[d * LDW + k] = f2bf(xb[(kk + k) * D_ + d]);
        }
        __syncthreads();

        bf16x8 af[5], bfr[4];
#pragma unroll
        for (int fm = 0; fm < 5; ++fm)
            af[fm] = *reinterpret_cast<const bf16x8*>(&wt[(wrow + fm * 16 + lm) * LDW + lk]);
#pragma unroll
        for (int fn = 0; fn < 4; ++fn)
            bfr[fn] = *reinterpret_cast<const bf16x8*>(&xt[(fn * 16 + lm) * LDW + lk]);
#pragma unroll
        for (int fm = 0; fm < 5; ++fm)
#pragma unroll
            for (int fn = 0; fn < 4; ++fn)
                acc[fm][fn] = __builtin_amdgcn_mfma_f32_16x16x32_bf16(
                    af[fm], bfr[fn], acc[fm][fn], 0, 0, 0);
    }

    // epilogue: BN1 affine + scatter to qkv[b][h][c][d]  (h = o&7, c = o>>3)
    const int lr4 = (lane >> 4) * 4;
#pragma unroll
    for (int fm = 0; fm < 5; ++fm) {
#pragma unroll
        for (int fn = 0; fn < 4; ++fn) {
            int d = fn * 16 + lm;
#pragma unroll
            for (int r = 0; r < 4; ++r) {
                int rl = wrow + fm * 16 + lr4 + r;   // local row 0..319
                int o  = row0 + rl;
                int hh = o & 7, cc = o >> 3;
                float val = acc[fm][fn][r] * ssc[rl] + ssh[rl];
                qkv[(((size_t)b * H_ + hh) * QKVC_ + cc) * D_ + d] = val;
            }
        }
    }
}

// ---------------------------------------------------------------------------
// K2: per (b,h): S = BN2(qr)+BN2(kr)+BN2(dots); attn = softmax(S);
//     result = BN3(kv) + BN3(out), where
//     out[i,d] = sum_j attn[d,j] v[i,j]
//     kv[i,d]  = sum_j attn[d,j] rel[16+i, 63+d-j]   (via gathered A2[d][u])
// Block = 256 threads, grid = 8192. f32 VALU; bf16 LDS for rel/attn/A2/v.
// ---------------------------------------------------------------------------
#define RLD 136   // padded u-stride (bf16/u32 rows): 16B-aligned, zero pad past 126
#define SA  72    // attn row stride in bf16 (144 B, 16B-aligned)

__global__ __launch_bounds__(256) void k2_attn(
    const float* __restrict__ qkv, const float* __restrict__ rel,
    const float* __restrict__ g2, const float* __restrict__ b2,
    const float* __restrict__ m2, const float* __restrict__ v2,
    const float* __restrict__ g3, const float* __restrict__ b3,
    const float* __restrict__ m3, const float* __restrict__ v3,
    float* __restrict__ outp)
{
    __shared__ float          qk[16 * 64];       // 4 KB   (q rows 0..7, k rows 8..15; [c][d])
    __shared__ unsigned short vvb[64 * 64];      // 8 KB   v as bf16, [i][j]
    __shared__ unsigned int   srelQK[8 * RLD];   // 4.25 KB packed (q-rel | k-rel) bf16 pairs
    __shared__ unsigned short srelv[64 * RLD];   // 17 KB  rel rows 16..79 as bf16
    __shared__ unsigned short attn[64 * SA];     // 9 KB   bf16
    __shared__ unsigned short A2[64 * RLD];      // 17 KB  gathered attn, bf16, zero-padded
    __shared__ float sc_kv[64], sc_o[64], sh3[64];

    const int tid = threadIdx.x;
    const int b   = blockIdx.x >> 3;
    const int h   = blockIdx.x & 7;
    const float* base = qkv + (((size_t)b * H_ + h) * QKVC_) * D_;

    // ---- stage ----
    for (int i = tid; i < 16 * 64; i += 256) qk[i] = base[i];
    for (int i = tid; i < 64 * 64; i += 256) vvb[i] = f2bf(base[16 * 64 + i]);
    for (int i = tid; i < 8 * RLD; i += 256) {
        int r = i / RLD, u = i - r * RLD;
        unsigned int pk = 0u;
        if (u < 127)
            pk = (unsigned int)f2bf(rel[r * 127 + u]) |
                 ((unsigned int)f2bf(rel[(8 + r) * 127 + u]) << 16);
        srelQK[i] = pk;
    }
    for (int i = tid; i < 64 * RLD; i += 256) {
        int r = i / RLD, u = i - r * RLD;
        srelv[i] = (u < 127) ? f2bf(rel[(16 + r) * 127 + u]) : (unsigned short)0;
        A2[i] = 0;
    }
    if (tid < 64) {
        int c = h * 64 + tid;
        float sa = g3[c] * rsqrtf(v3[c] + EPS_);
        float sb = g3[512 + c] * rsqrtf(v3[512 + c] + EPS_);
        sc_kv[tid] = sa;
        sc_o[tid]  = sb;
        sh3[tid]   = (b3[c] - m3[c] * sa) + (b3[512 + c] - m3[512 + c] * sb);
    }
    const int c2 = h * 3;
    const float s_qr = g2[c2]     * rsqrtf(v2[c2]     + EPS_);
    const float s_kr = g2[c2 + 1] * rsqrtf(v2[c2 + 1] + EPS_);
    const float s_dt = g2[c2 + 2] * rsqrtf(v2[c2 + 2] + EPS_);
    const float shS  = (b2[c2] - m2[c2] * s_qr) + (b2[c2 + 1] - m2[c2 + 1] * s_kr)
                     + (b2[c2 + 2] - m2[c2 + 2] * s_dt);

    __syncthreads();

    // ---- phase 1: scores. thread -> row d = tid>>2, j-range = (tid&3)*16 .. +16 ----
    const int d  = tid >> 2;
    const int jq = (tid & 3) * 16;
    float qd[8], kd[8];
#pragma unroll
    for (int i = 0; i < 8; ++i) { qd[i] = qk[i * 64 + d]; kd[i] = qk[(8 + i) * 64 + d]; }

    float sdt[16];
#pragma unroll
    for (int jj = 0; jj < 16; ++jj) sdt[jj] = 0.f;
#pragma unroll
    for (int i = 0; i < 8; ++i) {   // dots: vectorized k-row loads
        const f32x4* kp = reinterpret_cast<const f32x4*>(&qk[(8 + i) * 64 + jq]);
        f32x4 k0 = kp[0], k1 = kp[1], k2v = kp[2], k3 = kp[3];
        float qi = qd[i];
#pragma unroll
        for (int e = 0; e < 4; ++e) {
            sdt[e]      += qi * k0[e];
            sdt[4 + e]  += qi * k1[e];
            sdt[8 + e]  += qi * k2v[e];
            sdt[12 + e] += qi * k3[e];
        }
    }
    float s[16];
#pragma unroll
    for (int jj = 0; jj < 16; ++jj) {
        int u = 63 + d - (jq + jj);          // always in [0,126]
        float aqr = 0.f, akr = 0.f;
#pragma unroll
        for (int i = 0; i < 8; ++i) {
            unsigned int pk = srelQK[i * RLD + u];
            aqr += qd[i] * bf2f((unsigned short)(pk & 0xffffu));
            akr += kd[i] * bf2f((unsigned short)(pk >> 16));
        }
        s[jj] = s_qr * aqr + s_kr * akr + s_dt * sdt[jj] + shS;
    }

    // ---- phase 2: softmax over row d (4 lanes cooperate), write attn + A2 ----
    float mx = s[0];
#pragma unroll
    for (int jj = 1; jj < 16; ++jj) mx = fmaxf(mx, s[jj]);
    mx = fmaxf(mx, __shfl_xor(mx, 1));
    mx = fmaxf(mx, __shfl_xor(mx, 2));
    float sum = 0.f;
#pragma unroll
    for (int jj = 0; jj < 16; ++jj) { s[jj] = __expf(s[jj] - mx); sum += s[jj]; }
    sum += __shfl_xor(sum, 1);
    sum += __shfl_xor(sum, 2);
    const float inv = 1.f / sum;
#pragma unroll
    for (int jj = 0; jj < 16; ++jj) {
        int j = jq + jj;
        unsigned short pb = f2bf(s[jj] * inv);
        attn[d * SA + j] = pb;
        A2[d * RLD + (d + 63 - j)] = pb;     // u = 63+d-j in [d, d+63]
    }
    __syncthreads();

    // ---- phase 3: out & kv matmuls. thread tile: 4 i x 4 d (d strided by 16) ----
    const int i0 = (tid >> 4) * 4;
    const int db = tid & 15;
    float ao[4][4] = {{0.f}}, ak[4][4] = {{0.f}};

    for (int j0 = 0; j0 < 64; j0 += 8) {     // out part
        u16x8 a8[4], v8[4];
#pragma unroll
        for (int s4 = 0; s4 < 4; ++s4)
            a8[s4] = *reinterpret_cast<const u16x8*>(&attn[(db + 16 * s4) * SA + j0]);
#pragma unroll
        for (int ii = 0; ii < 4; ++ii)
            v8[ii] = *reinterpret_cast<const u16x8*>(&vvb[(i0 + ii) * 64 + j0]);
#pragma unroll
        for (int s4 = 0; s4 < 4; ++s4) {
            float af[8];
#pragma unroll
            for (int e = 0; e < 8; ++e) af[e] = bf2f(a8[s4][e]);
#pragma unroll
            for (int ii = 0; ii < 4; ++ii)
#pragma unroll
                for (int e = 0; e < 8; ++e)
                    ao[ii][s4] += bf2f(v8[ii][e]) * af[e];
        }
    }
    for (int u0 = 0; u0 < RLD; u0 += 8) {    // kv part (padded region is zeros)
        u16x8 a8[4], r8[4];
#pragma unroll
        for (int s4 = 0; s4 < 4; ++s4)
            a8[s4] = *reinterpret_cast<const u16x8*>(&A2[(db + 16 * s4) * RLD + u0]);
#pragma unroll
        for (int ii = 0; ii < 4; ++ii)
            r8[ii] = *reinterpret_cast<const u16x8*>(&srelv[(i0 + ii) * RLD + u0]);
#pragma unroll
        for (int s4 = 0; s4 < 4; ++s4) {
            float af[8];
#pragma unroll
            for (int e = 0; e < 8; ++e) af[e] = bf2f(a8[s4][e]);
#pragma unroll
            for (int ii = 0; ii < 4; ++ii)
#pragma unroll
                for (int e = 0; e < 8; ++e)
                    ak[ii][s4] += bf2f(r8[ii][e]) * af[e];
        }
    }

    // ---- BN3 + combine + store ----
    float* op = outp + ((size_t)b * 512 + h * 64) * 64;
#pragma unroll
    for (int ii = 0; ii < 4; ++ii) {
        int i = i0 + ii;
        float scv = sc_kv[i], sco = sc_o[i], sh = sh3[i];
#pragma unroll
        for (int s4 = 0; s4 < 4; ++s4) {
            int dd = db + 16 * s4;
            op[(size_t)i * 64 + dd] = scv * ak[ii][s4] + sco * ao[ii][s4] + sh;
        }
    }
}

extern "C" void kernel_launch(void* const* d_in, const int* in_sizes, int n_in,
                              void* d_out, int out_size, void* d_ws, size_t ws_size,
                              hipStream_t stream) {
    (void)in_sizes; (void)n_in; (void)out_size; (void)ws_size;
    const float* x   = (const float*)d_in[0];
    const float* w   = (const float*)d_in[1];
    const float* g1  = (const float*)d_in[2];
    const float* b1  = (const float*)d_in[3];
    const float* m1  = (const float*)d_in[4];
    const float* v1  = (const float*)d_in[5];
    const float* rel = (const float*)d_in[6];
    const float* g2  = (const float*)d_in[7];
    const float* b2  = (const float*)d_in[8];
    const float* m2  = (const float*)d_in[9];
    const float* v2  = (const float*)d_in[10];
    const float* g3  = (const float*)d_in[11];
    const float* b3  = (const float*)d_in[12];
    const float* m3  = (const float*)d_in[13];
    const float* v3  = (const float*)d_in[14];
    float* out = (float*)d_out;
    float* qkv = (float*)d_ws;   // 1024*8*80*64 f32 = 167.8 MB scratch

    hipLaunchKernelGGL(k1_gemm, dim3(2048), dim3(256), 0, stream,
                       x, w, g1, b1, m1, v1, qkv);
    hipLaunchKernelGGL(k2_attn, dim3(8192), dim3(256), 0, stream,
                       qkv, rel, g2, b2, m2, v2, g3, b3, m3, v3, out);
}

// Round 2
// 427.293 us; speedup vs baseline: 1.3966x; 1.3966x over previous
//
#include <hip/hip_runtime.h>
#include <hip/hip_bf16.h>

#define B_    1024
#define C_    512
#define H_    8
#define D_    64
#define QKVC_ 80
#define EPS_  1e-5f

typedef __attribute__((ext_vector_type(4))) float f32x4;
typedef __attribute__((ext_vector_type(8))) short bf16x8;
typedef __attribute__((ext_vector_type(8))) unsigned short u16x8;

__device__ __forceinline__ float bf2f(unsigned short h) {
    union { unsigned int u; float f; } c;
    c.u = ((unsigned int)h) << 16;
    return c.f;
}
__device__ __forceinline__ unsigned short f2bf(float f) {
    __hip_bfloat16 h = __float2bfloat16(f);
    return *reinterpret_cast<unsigned short*>(&h);
}

// ---------------------------------------------------------------------------
// K1: qkv[b,o,d] = BN1( sum_c conv_w[o,c] * x[b,c,d] )
// q,k channels (c<16) -> f32 ws array [b][h][16][64]
// v channels (c>=16)  -> bf16 ws array [b][h][64][64], pre-scaled by BN3 sc_o
// ---------------------------------------------------------------------------
#define MT  320
#define KT  32
#define LDW 40   // padded LDS row stride (bf16 elems)

__global__ __launch_bounds__(256) void k1_gemm(
    const float* __restrict__ x, const float* __restrict__ w,
    const float* __restrict__ g1, const float* __restrict__ b1,
    const float* __restrict__ m1, const float* __restrict__ v1,
    const float* __restrict__ g3, const float* __restrict__ v3,
    float* __restrict__ qkf, unsigned short* __restrict__ qkb)
{
    __shared__ unsigned short wt[MT * LDW];   // 25600 B
    __shared__ unsigned short xt[64 * LDW];   // 5120 B  (x transposed: xt[d][k])
    __shared__ float ssc[MT], ssh[MT];

    const int tid  = threadIdx.x;
    const int b    = blockIdx.x >> 1;
    const int row0 = (blockIdx.x & 1) * MT;

    for (int t = tid; t < MT; t += 256) {
        int o = row0 + t;
        float sc = g1[o] * rsqrtf(v1[o] + EPS_);
        float sh = b1[o] - m1[o] * sc;
        int cc = o >> 3, hh = o & 7;
        if (cc >= 16) {                       // fold BN3 sc_o into v channels
            int c3 = 512 + hh * 64 + (cc - 16);
            float f = g3[c3] * rsqrtf(v3[c3] + EPS_);
            sc *= f; sh *= f;
        }
        ssc[t] = sc;
        ssh[t] = sh;
    }

    const int lane = tid & 63;
    const int wv   = tid >> 6;
    const int wrow = wv * 80;
    const int lm   = lane & 15;
    const int lk   = (lane >> 4) * 8;

    f32x4 acc[5][4];
#pragma unroll
    for (int i = 0; i < 5; ++i)
#pragma unroll
        for (int j = 0; j < 4; ++j) acc[i][j] = (f32x4){0.f, 0.f, 0.f, 0.f};

    const float* xb = x + (size_t)b * C_ * D_;

    for (int kk = 0; kk < C_; kk += KT) {
        __syncthreads();
#pragma unroll
        for (int it = 0; it < 20; ++it) {
            int idx = tid + it * 256;
            int r   = idx >> 4;
            int cp  = (idx & 15) * 2;
            const float2 a = *reinterpret_cast<const float2*>(
                w + (size_t)(row0 + r) * C_ + kk + cp);
            unsigned int pk = (unsigned int)f2bf(a.x) | ((unsigned int)f2bf(a.y) << 16);
            *reinterpret_cast<unsigned int*>(&wt[r * LDW + cp]) = pk;
        }
#pragma unroll
        for (int it = 0; it < 8; ++it) {
            int idx = tid + it * 256;
            int k   = idx >> 6;
            int d   = idx & 63;
            xt[d * LDW + k] = f2bf(xb[(kk + k) * D_ + d]);
        }
        __syncthreads();

        bf16x8 af[5], bfr[4];
#pragma unroll
        for (int fm = 0; fm < 5; ++fm)
            af[fm] = *reinterpret_cast<const bf16x8*>(&wt[(wrow + fm * 16 + lm) * LDW + lk]);
#pragma unroll
        for (int fn = 0; fn < 4; ++fn)
            bfr[fn] = *reinterpret_cast<const bf16x8*>(&xt[(fn * 16 + lm) * LDW + lk]);
#pragma unroll
        for (int fm = 0; fm < 5; ++fm)
#pragma unroll
            for (int fn = 0; fn < 4; ++fn)
                acc[fm][fn] = __builtin_amdgcn_mfma_f32_16x16x32_bf16(
                    af[fm], bfr[fn], acc[fm][fn], 0, 0, 0);
    }

    const int lr4 = (lane >> 4) * 4;
#pragma unroll
    for (int fm = 0; fm < 5; ++fm) {
#pragma unroll
        for (int fn = 0; fn < 4; ++fn) {
            int d = fn * 16 + lm;
#pragma unroll
            for (int r = 0; r < 4; ++r) {
                int rl = wrow + fm * 16 + lr4 + r;
                int o  = row0 + rl;
                int hh = o & 7, cc = o >> 3;
                float val = acc[fm][fn][r] * ssc[rl] + ssh[rl];
                if (cc < 16)
                    qkf[(((size_t)b * H_ + hh) * 16 + cc) * 64 + d] = val;
                else
                    qkb[(((size_t)b * H_ + hh) * 64 + (cc - 16)) * 64 + d] = f2bf(val);
            }
        }
    }
}

// ---------------------------------------------------------------------------
// K2: per (b,h): scores -> softmax -> MFMA phase 3:
//   acc[i,d] = sum_j v'[i,j]*attn[d,j] + sum_u relv'[i,u]*A2[d,u]
//   (v' pre-scaled by sc_o in K1; relv' pre-scaled by sc_kv at staging)
//   out = acc + sh3[i]
// ---------------------------------------------------------------------------
#define RLD 136   // bf16 row stride for srelv/A2: 272 B == 4 banks mod 32 -> 2-way
#define SA  72    // bf16 row stride for vvb/attn: 144 B == 4 banks mod 32 -> 2-way

__global__ __launch_bounds__(256) void k2_attn(
    const float* __restrict__ qkf, const unsigned short* __restrict__ qkb,
    const float* __restrict__ rel,
    const float* __restrict__ g2, const float* __restrict__ b2,
    const float* __restrict__ m2, const float* __restrict__ v2,
    const float* __restrict__ g3, const float* __restrict__ b3,
    const float* __restrict__ m3, const float* __restrict__ v3,
    float* __restrict__ outp)
{
    __shared__ float          qk[16 * 64];       // 4 KB  q rows 0..7, k rows 8..15
    __shared__ unsigned short vvb[64 * SA];      // 9216  v' bf16 [i][j]
    __shared__ unsigned short attn[64 * SA];     // 9216  bf16 [d][j]
    __shared__ unsigned short srelv[64 * RLD];   // 17408 relv' bf16 [i][u], zero-pad
    __shared__ unsigned short A2[64 * RLD];      // 17408 gathered attn [d][u], zero-pad
    __shared__ unsigned int   srelQK[8 * RLD];   // 4352  packed (q-rel|k-rel) bf16
    __shared__ float sc_kv[64], sh3[64];

    const int tid = threadIdx.x;
    const int b   = blockIdx.x >> 3;
    const int h   = blockIdx.x & 7;
    const float* qkbase = qkf + (((size_t)b * H_ + h) * 16) * 64;
    const unsigned short* vbase = qkb + (((size_t)b * H_ + h) * 64) * 64;

    // ---- stage (scale-independent) ----
    {   // qk: 1024 f32, one f32x4 per thread
        int i4 = tid * 4;
        *reinterpret_cast<f32x4*>(&qk[i4]) = *reinterpret_cast<const f32x4*>(&qkbase[i4]);
    }
    {   // v' copy (already scaled bf16): row r, 16 cols
        int r = tid >> 2, c0 = (tid & 3) * 16;
        u16x8 a = *reinterpret_cast<const u16x8*>(&vbase[r * 64 + c0]);
        u16x8 bq = *reinterpret_cast<const u16x8*>(&vbase[r * 64 + c0 + 8]);
        *reinterpret_cast<u16x8*>(&vvb[r * SA + c0]) = a;
        *reinterpret_cast<u16x8*>(&vvb[r * SA + c0 + 8]) = bq;
    }
    for (int i = tid; i < 8 * 128; i += 256) {   // packed q-rel|k-rel
        int r = i >> 7, u = i & 127;
        unsigned int pk = 0u;
        if (u < 127)
            pk = (unsigned int)f2bf(rel[r * 127 + u]) |
                 ((unsigned int)f2bf(rel[(8 + r) * 127 + u]) << 16);
        srelQK[r * RLD + u] = pk;
    }
    for (int i = tid; i < 64 * RLD / 2; i += 256)   // zero A2
        reinterpret_cast<unsigned int*>(A2)[i] = 0u;
    if (tid < 64) {
        int c = h * 64 + tid;
        float sa = g3[c] * rsqrtf(v3[c] + EPS_);
        float sb = g3[512 + c] * rsqrtf(v3[512 + c] + EPS_);
        sc_kv[tid] = sa;
        sh3[tid]   = (b3[c] - m3[c] * sa) + (b3[512 + c] - m3[512 + c] * sb);
    }
    __syncthreads();

    // ---- stage srelv (needs sc_kv) ----
    for (int i = tid; i < 64 * 64; i += 256) {
        int r = i >> 6, up = i & 63;
        int u = up * 2;
        float s = sc_kv[r];
        float a0 = rel[(16 + r) * 127 + u];
        float a1 = (up < 63) ? rel[(16 + r) * 127 + u + 1] : 0.f;
        unsigned int pk = (unsigned int)f2bf(a0 * s) | ((unsigned int)f2bf(a1 * s) << 16);
        *reinterpret_cast<unsigned int*>(&srelv[r * RLD + u]) = pk;
    }
    {   // zero-pad srelv u = 128..135
        int r = tid >> 2, q = tid & 3;
        *reinterpret_cast<unsigned int*>(&srelv[r * RLD + 128 + q * 2]) = 0u;
    }

    const int c2 = h * 3;
    const float s_qr = g2[c2]     * rsqrtf(v2[c2]     + EPS_);
    const float s_kr = g2[c2 + 1] * rsqrtf(v2[c2 + 1] + EPS_);
    const float s_dt = g2[c2 + 2] * rsqrtf(v2[c2 + 2] + EPS_);
    const float shS  = (b2[c2] - m2[c2] * s_qr) + (b2[c2 + 1] - m2[c2 + 1] * s_kr)
                     + (b2[c2 + 2] - m2[c2 + 2] * s_dt);

    __syncthreads();

    // ---- phase 1: scores. thread -> row d = tid>>2, j-range = (tid&3)*16 ----
    const int d  = tid >> 2;
    const int jq = (tid & 3) * 16;
    float qd[8], kd[8];
#pragma unroll
    for (int i = 0; i < 8; ++i) { qd[i] = qk[i * 64 + d]; kd[i] = qk[(8 + i) * 64 + d]; }

    float sdt[16];
#pragma unroll
    for (int jj = 0; jj < 16; ++jj) sdt[jj] = 0.f;
#pragma unroll
    for (int i = 0; i < 8; ++i) {
        const f32x4* kp = reinterpret_cast<const f32x4*>(&qk[(8 + i) * 64 + jq]);
        f32x4 k0 = kp[0], k1 = kp[1], k2v = kp[2], k3 = kp[3];
        float qi = qd[i];
#pragma unroll
        for (int e = 0; e < 4; ++e) {
            sdt[e]      += qi * k0[e];
            sdt[4 + e]  += qi * k1[e];
            sdt[8 + e]  += qi * k2v[e];
            sdt[12 + e] += qi * k3[e];
        }
    }
    float s[16];
#pragma unroll
    for (int jj = 0; jj < 16; ++jj) {
        int u = 63 + d - (jq + jj);
        float aqr = 0.f, akr = 0.f;
#pragma unroll
        for (int i = 0; i < 8; ++i) {
            unsigned int pk = srelQK[i * RLD + u];
            aqr += qd[i] * bf2f((unsigned short)(pk & 0xffffu));
            akr += kd[i] * bf2f((unsigned short)(pk >> 16));
        }
        s[jj] = s_qr * aqr + s_kr * akr + s_dt * sdt[jj] + shS;
    }

    // ---- phase 2: softmax (4 lanes/row) ----
    float mx = s[0];
#pragma unroll
    for (int jj = 1; jj < 16; ++jj) mx = fmaxf(mx, s[jj]);
    mx = fmaxf(mx, __shfl_xor(mx, 1));
    mx = fmaxf(mx, __shfl_xor(mx, 2));
    float sum = 0.f;
#pragma unroll
    for (int jj = 0; jj < 16; ++jj) { s[jj] = __expf(s[jj] - mx); sum += s[jj]; }
    sum += __shfl_xor(sum, 1);
    sum += __shfl_xor(sum, 2);
    const float inv = 1.f / sum;
#pragma unroll
    for (int jj = 0; jj < 16; jj += 2) {
        int j = jq + jj;
        unsigned short p0 = f2bf(s[jj] * inv);
        unsigned short p1 = f2bf(s[jj + 1] * inv);
        *reinterpret_cast<unsigned int*>(&attn[d * SA + j]) =
            (unsigned int)p0 | ((unsigned int)p1 << 16);
        A2[d * RLD + (d + 63 - j)]     = p0;
        A2[d * RLD + (d + 63 - j - 1)] = p1;
    }
    __syncthreads();

    // ---- phase 3: MFMA. wave w owns i-strip [16w,16w+16), all d ----
    const int lane = tid & 63;
    const int i0w  = (tid >> 6) * 16;
    const int lm   = lane & 15;
    const int lk8  = (lane >> 4) * 8;

    f32x4 acc[4];
#pragma unroll
    for (int nf = 0; nf < 4; ++nf) acc[nf] = (f32x4){0.f, 0.f, 0.f, 0.f};

    const bf16x8 av0 = *reinterpret_cast<const bf16x8*>(&vvb[(i0w + lm) * SA + lk8]);
    const bf16x8 av1 = *reinterpret_cast<const bf16x8*>(&vvb[(i0w + lm) * SA + 32 + lk8]);
    const unsigned short* srow = &srelv[(i0w + lm) * RLD + lk8];
    const bf16x8 ar0 = *reinterpret_cast<const bf16x8*>(&srow[0]);
    const bf16x8 ar1 = *reinterpret_cast<const bf16x8*>(&srow[32]);
    const bf16x8 ar2 = *reinterpret_cast<const bf16x8*>(&srow[64]);
    const bf16x8 ar3 = *reinterpret_cast<const bf16x8*>(&srow[96]);

#pragma unroll
    for (int nf = 0; nf < 4; ++nf) {
        const unsigned short* arow = &attn[(nf * 16 + lm) * SA + lk8];
        acc[nf] = __builtin_amdgcn_mfma_f32_16x16x32_bf16(
            av0, *reinterpret_cast<const bf16x8*>(&arow[0]), acc[nf], 0, 0, 0);
        acc[nf] = __builtin_amdgcn_mfma_f32_16x16x32_bf16(
            av1, *reinterpret_cast<const bf16x8*>(&arow[32]), acc[nf], 0, 0, 0);
        const unsigned short* a2row = &A2[(nf * 16 + lm) * RLD + lk8];
        acc[nf] = __builtin_amdgcn_mfma_f32_16x16x32_bf16(
            ar0, *reinterpret_cast<const bf16x8*>(&a2row[0]), acc[nf], 0, 0, 0);
        acc[nf] = __builtin_amdgcn_mfma_f32_16x16x32_bf16(
            ar1, *reinterpret_cast<const bf16x8*>(&a2row[32]), acc[nf], 0, 0, 0);
        acc[nf] = __builtin_amdgcn_mfma_f32_16x16x32_bf16(
            ar2, *reinterpret_cast<const bf16x8*>(&a2row[64]), acc[nf], 0, 0, 0);
        acc[nf] = __builtin_amdgcn_mfma_f32_16x16x32_bf16(
            ar3, *reinterpret_cast<const bf16x8*>(&a2row[96]), acc[nf], 0, 0, 0);
    }

    // ---- epilogue: + sh3[i], store ----
    float* op = outp + ((size_t)b * 512 + h * 64) * 64;
    const int r0 = (lane >> 4) * 4;
#pragma unroll
    for (int r = 0; r < 4; ++r) {
        int i = i0w + r0 + r;
        float sh = sh3[i];
#pragma unroll
        for (int nf = 0; nf < 4; ++nf)
            op[(size_t)i * 64 + nf * 16 + lm] = acc[nf][r] + sh;
    }
}

extern "C" void kernel_launch(void* const* d_in, const int* in_sizes, int n_in,
                              void* d_out, int out_size, void* d_ws, size_t ws_size,
                              hipStream_t stream) {
    (void)in_sizes; (void)n_in; (void)out_size; (void)ws_size;
    const float* x   = (const float*)d_in[0];
    const float* w   = (const float*)d_in[1];
    const float* g1  = (const float*)d_in[2];
    const float* b1  = (const float*)d_in[3];
    const float* m1  = (const float*)d_in[4];
    const float* v1  = (const float*)d_in[5];
    const float* rel = (const float*)d_in[6];
    const float* g2  = (const float*)d_in[7];
    const float* b2  = (const float*)d_in[8];
    const float* m2  = (const float*)d_in[9];
    const float* v2  = (const float*)d_in[10];
    const float* g3  = (const float*)d_in[11];
    const float* b3  = (const float*)d_in[12];
    const float* m3  = (const float*)d_in[13];
    const float* v3  = (const float*)d_in[14];
    float* out = (float*)d_out;

    float* qkf          = (float*)d_ws;                       // 33.55 MB
    unsigned short* qkb = (unsigned short*)((char*)d_ws + (size_t)33554432); // 67.1 MB

    hipLaunchKernelGGL(k1_gemm, dim3(2048), dim3(256), 0, stream,
                       x, w, g1, b1, m1, v1, g3, v3, qkf, qkb);
    hipLaunchKernelGGL(k2_attn, dim3(8192), dim3(256), 0, stream,
                       qkf, qkb, rel, g2, b2, m2, v2, g3, b3, m3, v3, out);
}

// Round 3
// 324.245 us; speedup vs baseline: 1.8404x; 1.3178x over previous
//
#include <hip/hip_runtime.h>
#include <hip/hip_bf16.h>

#define B_    1024
#define C_    512
#define H_    8
#define D_    64
#define QKVC_ 80
#define EPS_  1e-5f

typedef __attribute__((ext_vector_type(4))) float f32x4;
typedef __attribute__((ext_vector_type(4))) unsigned int u32x4;
typedef __attribute__((ext_vector_type(8))) short bf16x8;
typedef __attribute__((ext_vector_type(8))) unsigned short u16x8;

__device__ __forceinline__ float bf2f(unsigned short h) {
    union { unsigned int u; float f; } c;
    c.u = ((unsigned int)h) << 16;
    return c.f;
}
__device__ __forceinline__ unsigned short f2bf(float f) {
    __hip_bfloat16 h = __float2bfloat16(f);
    return *reinterpret_cast<unsigned short*>(&h);
}
__device__ __forceinline__ float lo_bf(unsigned int w) {
    union { unsigned int u; float f; } c; c.u = w << 16; return c.f;
}
__device__ __forceinline__ float hi_bf(unsigned int w) {
    union { unsigned int u; float f; } c; c.u = w & 0xffff0000u; return c.f;
}

// ---------------------------------------------------------------------------
// K0: convert conv_w (640x512 f32) -> bf16 packed in MFMA A-fragment order.
// frag f = (o>>4)*16 + (c>>5); lane l = (o&15) | (((c>>3)&3)<<4); elem = c&7.
// ---------------------------------------------------------------------------
__global__ __launch_bounds__(256) void k0_wconv(
    const float* __restrict__ w, unsigned short* __restrict__ wf)
{
    int t = blockIdx.x * 256 + threadIdx.x;       // 0..40959
    int o  = t >> 6;
    int c0 = (t & 63) * 8;
    const float* src = w + (size_t)o * C_ + c0;
    u16x8 p;
#pragma unroll
    for (int e = 0; e < 8; ++e) p[e] = f2bf(src[e]);
    int f = (o >> 4) * 16 + (c0 >> 5);
    int l = (o & 15) | (((c0 >> 3) & 3) << 4);
    *reinterpret_cast<u16x8*>(&wf[(size_t)f * 1024 + l * 8]) = p;
}

// ---------------------------------------------------------------------------
// K1: qkv[b,o,d] = BN1( sum_c conv_w[o,c] * x[b,c,d] )
// A-fragments straight from global wf (L2-resident). LDS stages only x^T.
// q,k channels (c<16) -> f32 [b][h][16][64]; v channels -> bf16 * sc_o.
// ---------------------------------------------------------------------------
#define MT  320
#define KT  32
#define LDW 40

__global__ __launch_bounds__(256) void k1_gemm(
    const float* __restrict__ x, const unsigned short* __restrict__ wf,
    const float* __restrict__ g1, const float* __restrict__ b1,
    const float* __restrict__ m1, const float* __restrict__ v1,
    const float* __restrict__ g3, const float* __restrict__ v3,
    float* __restrict__ qkf, unsigned short* __restrict__ qkb)
{
    __shared__ unsigned short xt[64 * LDW];   // 5120 B  xt[d][k]
    __shared__ float ssc[MT], ssh[MT];

    const int tid  = threadIdx.x;
    const int b    = blockIdx.x >> 1;
    const int row0 = (blockIdx.x & 1) * MT;

    for (int t = tid; t < MT; t += 256) {
        int o = row0 + t;
        float sc = g1[o] * rsqrtf(v1[o] + EPS_);
        float sh = b1[o] - m1[o] * sc;
        int cc = o >> 3, hh = o & 7;
        if (cc >= 16) {
            int c3 = 512 + hh * 64 + (cc - 16);
            float f = g3[c3] * rsqrtf(v3[c3] + EPS_);
            sc *= f; sh *= f;
        }
        ssc[t] = sc;
        ssh[t] = sh;
    }

    const int lane = tid & 63;
    const int wv   = tid >> 6;
    const int wrow = wv * 80;
    const int lm   = lane & 15;
    const int lk   = (lane >> 4) * 8;

    f32x4 acc[5][4];
#pragma unroll
    for (int i = 0; i < 5; ++i)
#pragma unroll
        for (int j = 0; j < 4; ++j) acc[i][j] = (f32x4){0.f, 0.f, 0.f, 0.f};

    const float* xb = x + (size_t)b * C_ * D_;

    for (int kk = 0; kk < C_; kk += KT) {
        __syncthreads();
        // issue A-fragment global loads early (overlap with staging)
        bf16x8 af[5];
#pragma unroll
        for (int fm = 0; fm < 5; ++fm) {
            int rb = row0 + wrow + fm * 16;                  // 16-aligned
            size_t fidx = (size_t)((rb >> 4) * 16 + (kk >> 5)) * 1024 + lane * 8;
            af[fm] = *reinterpret_cast<const bf16x8*>(&wf[fidx]);
        }
        // stage x tile transposed: xt[d][k], packed u32 (k-pairs)
#pragma unroll
        for (int it = 0; it < 4; ++it) {
            int p  = tid + it * 256;     // 0..1023
            int kp = p >> 6;             // 0..15
            int dd = p & 63;
            float a0 = xb[(kk + 2 * kp) * D_ + dd];
            float a1 = xb[(kk + 2 * kp + 1) * D_ + dd];
            unsigned int pk = (unsigned int)f2bf(a0) | ((unsigned int)f2bf(a1) << 16);
            *reinterpret_cast<unsigned int*>(&xt[dd * LDW + 2 * kp]) = pk;
        }
        __syncthreads();

        bf16x8 bfr[4];
#pragma unroll
        for (int fn = 0; fn < 4; ++fn)
            bfr[fn] = *reinterpret_cast<const bf16x8*>(&xt[(fn * 16 + lm) * LDW + lk]);
#pragma unroll
        for (int fm = 0; fm < 5; ++fm)
#pragma unroll
            for (int fn = 0; fn < 4; ++fn)
                acc[fm][fn] = __builtin_amdgcn_mfma_f32_16x16x32_bf16(
                    af[fm], bfr[fn], acc[fm][fn], 0, 0, 0);
    }

    const int lr4 = (lane >> 4) * 4;
#pragma unroll
    for (int fm = 0; fm < 5; ++fm) {
#pragma unroll
        for (int fn = 0; fn < 4; ++fn) {
            int d = fn * 16 + lm;
#pragma unroll
            for (int r = 0; r < 4; ++r) {
                int rl = wrow + fm * 16 + lr4 + r;
                int o  = row0 + rl;
                int hh = o & 7, cc = o >> 3;
                float val = acc[fm][fn][r] * ssc[rl] + ssh[rl];
                if (cc < 16)
                    qkf[(((size_t)b * H_ + hh) * 16 + cc) * 64 + d] = val;
                else
                    qkb[(((size_t)b * H_ + hh) * 64 + (cc - 16)) * 64 + d] = f2bf(val);
            }
        }
    }
}

// ---------------------------------------------------------------------------
// K2: per (b,h): scores -> softmax -> MFMA phase 3.
// LDS: qk(f32) + attn + A2 + relt (u-major swizzled gather table) = 35.3 KB.
// v / rel_v feed phase-3 MFMA as register A-fragments from global.
// ---------------------------------------------------------------------------
#define RLD 136   // A2 row stride (bf16): 272 B -> 2-way banks
#define SA  72    // attn row stride (bf16): 144 B -> 2-way banks

__global__ __launch_bounds__(256) void k2_attn(
    const float* __restrict__ qkf, const unsigned short* __restrict__ qkb,
    const float* __restrict__ rel,
    const float* __restrict__ g2, const float* __restrict__ b2,
    const float* __restrict__ m2, const float* __restrict__ v2,
    const float* __restrict__ g3, const float* __restrict__ b3,
    const float* __restrict__ m3, const float* __restrict__ v3,
    float* __restrict__ outp)
{
    __shared__ float          qk[16 * 64];      // 4096
    __shared__ unsigned short attn[64 * SA];    // 9216
    __shared__ unsigned short A2[64 * RLD];     // 17408
    __shared__ unsigned int   relt[128 * 8];    // 4096  u-major (rq|rk) pairs, swizzled
    __shared__ float sh3[64];

    const int tid = threadIdx.x;
    const int b   = blockIdx.x >> 3;
    const int h   = blockIdx.x & 7;
    const float* qkbase = qkf + (((size_t)b * H_ + h) * 16) * 64;
    const unsigned short* vbase = qkb + (((size_t)b * H_ + h) * 64) * 64;

    // ---- stage ----
    {   // qk: one f32x4 per thread
        int i4 = tid * 4;
        *reinterpret_cast<f32x4*>(&qk[i4]) = *reinterpret_cast<const f32x4*>(&qkbase[i4]);
    }
    for (int i = tid; i < 127 * 8; i += 256) {   // relt, transposed + half-swizzled
        int u = i >> 3, ii = i & 7;
        unsigned int pk = (unsigned int)f2bf(rel[ii * 127 + u]) |
                          ((unsigned int)f2bf(rel[(8 + ii) * 127 + u]) << 16);
        relt[u * 8 + (ii ^ (((u >> 2) & 1) << 2))] = pk;
    }
    for (int i = tid; i < 64 * RLD / 2; i += 256)
        reinterpret_cast<unsigned int*>(A2)[i] = 0u;
    if (tid < 64) {
        int c = h * 64 + tid;
        float sa = g3[c] * rsqrtf(v3[c] + EPS_);
        float sb = g3[512 + c] * rsqrtf(v3[512 + c] + EPS_);
        sh3[tid] = (b3[c] - m3[c] * sa) + (b3[512 + c] - m3[512 + c] * sb);
    }
    const int c2 = h * 3;
    const float s_qr = g2[c2]     * rsqrtf(v2[c2]     + EPS_);
    const float s_kr = g2[c2 + 1] * rsqrtf(v2[c2 + 1] + EPS_);
    const float s_dt = g2[c2 + 2] * rsqrtf(v2[c2 + 2] + EPS_);
    const float shS  = (b2[c2] - m2[c2] * s_qr) + (b2[c2 + 1] - m2[c2 + 1] * s_kr)
                     + (b2[c2 + 2] - m2[c2 + 2] * s_dt);

    __syncthreads();

    // ---- phase 1: scores. thread -> row d = tid>>2, j-range (tid&3)*16 ----
    const int d  = tid >> 2;
    const int jq = (tid & 3) * 16;
    float qd[8], kd[8];
#pragma unroll
    for (int i = 0; i < 8; ++i) { qd[i] = qk[i * 64 + d]; kd[i] = qk[(8 + i) * 64 + d]; }

    float sdt[16];
#pragma unroll
    for (int jj = 0; jj < 16; ++jj) sdt[jj] = 0.f;
#pragma unroll
    for (int i = 0; i < 8; ++i) {
        const f32x4* kp = reinterpret_cast<const f32x4*>(&qk[(8 + i) * 64 + jq]);
        f32x4 k0 = kp[0], k1 = kp[1], k2v = kp[2], k3 = kp[3];
        float qi = qd[i];
#pragma unroll
        for (int e = 0; e < 4; ++e) {
            sdt[e]      += qi * k0[e];
            sdt[4 + e]  += qi * k1[e];
            sdt[8 + e]  += qi * k2v[e];
            sdt[12 + e] += qi * k3[e];
        }
    }
    float s[16];
#pragma unroll
    for (int jj = 0; jj < 16; ++jj) {
        int u = 63 + d - jq - jj;                 // in [0,126]
        const unsigned int* row = &relt[u * 8];
        int sw = ((u >> 2) & 1) << 2;
        u32x4 w0 = *reinterpret_cast<const u32x4*>(&row[sw]);       // i 0..3
        u32x4 w1 = *reinterpret_cast<const u32x4*>(&row[sw ^ 4]);   // i 4..7
        float aqr = 0.f, akr = 0.f;
#pragma unroll
        for (int e = 0; e < 4; ++e) {
            aqr += qd[e]     * lo_bf(w0[e]);
            akr += kd[e]     * hi_bf(w0[e]);
            aqr += qd[4 + e] * lo_bf(w1[e]);
            akr += kd[4 + e] * hi_bf(w1[e]);
        }
        s[jj] = s_qr * aqr + s_kr * akr + s_dt * sdt[jj] + shS;
    }

    // ---- phase 2: softmax (4 lanes/row) ----
    float mx = s[0];
#pragma unroll
    for (int jj = 1; jj < 16; ++jj) mx = fmaxf(mx, s[jj]);
    mx = fmaxf(mx, __shfl_xor(mx, 1));
    mx = fmaxf(mx, __shfl_xor(mx, 2));
    float sum = 0.f;
#pragma unroll
    for (int jj = 0; jj < 16; ++jj) { s[jj] = __expf(s[jj] - mx); sum += s[jj]; }
    sum += __shfl_xor(sum, 1);
    sum += __shfl_xor(sum, 2);
    const float inv = 1.f / sum;
#pragma unroll
    for (int jj = 0; jj < 16; jj += 2) {
        int j = jq + jj;
        unsigned short p0 = f2bf(s[jj] * inv);
        unsigned short p1 = f2bf(s[jj + 1] * inv);
        *reinterpret_cast<unsigned int*>(&attn[d * SA + j]) =
            (unsigned int)p0 | ((unsigned int)p1 << 16);
        A2[d * RLD + (d + 63 - j)]     = p0;
        A2[d * RLD + (d + 63 - j - 1)] = p1;
    }

    // ---- load phase-3 A-fragments into registers (global; overlaps barrier) ----
    const int lane = tid & 63;
    const int i0w  = (tid >> 6) * 16;
    const int lm   = lane & 15;
    const int lk8  = (lane >> 4) * 8;
    const int irow = i0w + lm;

    u16x8 av0 = *reinterpret_cast<const u16x8*>(&vbase[irow * 64 + lk8]);
    u16x8 av1 = *reinterpret_cast<const u16x8*>(&vbase[irow * 64 + 32 + lk8]);
    union BF8 { u16x8 u; bf16x8 v; } arx[4];
    {
        int c3 = h * 64 + irow;
        float scl = g3[c3] * rsqrtf(v3[c3] + EPS_);
        const float* rrow = rel + (size_t)(16 + irow) * 127;
#pragma unroll
        for (int t = 0; t < 4; ++t) {
            int ub = lk8 + t * 32;
#pragma unroll
            for (int e = 0; e < 8; ++e) {
                int u = ub + e;
                float xv = (u < 127) ? rrow[u] : 0.f;
                arx[t].u[e] = f2bf(xv * scl);
            }
        }
    }

    __syncthreads();

    // ---- phase 3: MFMA. wave w owns i-strip [16w,16w+16) ----
    f32x4 acc[4];
#pragma unroll
    for (int nf = 0; nf < 4; ++nf) acc[nf] = (f32x4){0.f, 0.f, 0.f, 0.f};

    const bf16x8 bav0 = *reinterpret_cast<const bf16x8*>(&av0);
    const bf16x8 bav1 = *reinterpret_cast<const bf16x8*>(&av1);

#pragma unroll
    for (int nf = 0; nf < 4; ++nf) {
        const unsigned short* arow = &attn[(nf * 16 + lm) * SA + lk8];
        acc[nf] = __builtin_amdgcn_mfma_f32_16x16x32_bf16(
            bav0, *reinterpret_cast<const bf16x8*>(&arow[0]), acc[nf], 0, 0, 0);
        acc[nf] = __builtin_amdgcn_mfma_f32_16x16x32_bf16(
            bav1, *reinterpret_cast<const bf16x8*>(&arow[32]), acc[nf], 0, 0, 0);
        const unsigned short* a2row = &A2[(nf * 16 + lm) * RLD + lk8];
        acc[nf] = __builtin_amdgcn_mfma_f32_16x16x32_bf16(
            arx[0].v, *reinterpret_cast<const bf16x8*>(&a2row[0]), acc[nf], 0, 0, 0);
        acc[nf] = __builtin_amdgcn_mfma_f32_16x16x32_bf16(
            arx[1].v, *reinterpret_cast<const bf16x8*>(&a2row[32]), acc[nf], 0, 0, 0);
        acc[nf] = __builtin_amdgcn_mfma_f32_16x16x32_bf16(
            arx[2].v, *reinterpret_cast<const bf16x8*>(&a2row[64]), acc[nf], 0, 0, 0);
        acc[nf] = __builtin_amdgcn_mfma_f32_16x16x32_bf16(
            arx[3].v, *reinterpret_cast<const bf16x8*>(&a2row[96]), acc[nf], 0, 0, 0);
    }

    // ---- epilogue ----
    float* op = outp + ((size_t)b * 512 + h * 64) * 64;
    const int r0 = (lane >> 4) * 4;
#pragma unroll
    for (int r = 0; r < 4; ++r) {
        int i = i0w + r0 + r;
        float sh = sh3[i];
#pragma unroll
        for (int nf = 0; nf < 4; ++nf)
            op[(size_t)i * 64 + nf * 16 + lm] = acc[nf][r] + sh;
    }
}

extern "C" void kernel_launch(void* const* d_in, const int* in_sizes, int n_in,
                              void* d_out, int out_size, void* d_ws, size_t ws_size,
                              hipStream_t stream) {
    (void)in_sizes; (void)n_in; (void)out_size; (void)ws_size;
    const float* x   = (const float*)d_in[0];
    const float* w   = (const float*)d_in[1];
    const float* g1  = (const float*)d_in[2];
    const float* b1  = (const float*)d_in[3];
    const float* m1  = (const float*)d_in[4];
    const float* v1  = (const float*)d_in[5];
    const float* rel = (const float*)d_in[6];
    const float* g2  = (const float*)d_in[7];
    const float* b2  = (const float*)d_in[8];
    const float* m2  = (const float*)d_in[9];
    const float* v2  = (const float*)d_in[10];
    const float* g3  = (const float*)d_in[11];
    const float* b3  = (const float*)d_in[12];
    const float* m3  = (const float*)d_in[13];
    const float* v3  = (const float*)d_in[14];
    float* out = (float*)d_out;

    // ws layout: w_frag (1.31 MB, padded to 1.5 MB) | qkf (33.55 MB) | qkb (67.1 MB)
    unsigned short* wfrag = (unsigned short*)d_ws;
    float* qkf          = (float*)((char*)d_ws + (size_t)1572864);
    unsigned short* qkb = (unsigned short*)((char*)d_ws + (size_t)1572864 + 33554432);

    hipLaunchKernelGGL(k0_wconv, dim3(160), dim3(256), 0, stream, w, wfrag);
    hipLaunchKernelGGL(k1_gemm, dim3(2048), dim3(256), 0, stream,
                       x, wfrag, g1, b1, m1, v1, g3, v3, qkf, qkb);
    hipLaunchKernelGGL(k2_attn, dim3(8192), dim3(256), 0, stream,
                       qkf, qkb, rel, g2, b2, m2, v2, g3, b3, m3, v3, out);
}

// Round 6
// 203.360 us; speedup vs baseline: 2.9344x; 1.5944x over previous
//
#include <hip/hip_runtime.h>
#include <hip/hip_bf16.h>

#define B_    1024
#define C_    512
#define H_    8
#define D_    64
#define EPS_  1e-5f

typedef __attribute__((ext_vector_type(4))) float f32x4;
typedef __attribute__((ext_vector_type(8))) short bf16x8;
typedef __attribute__((ext_vector_type(8))) unsigned short u16x8;

__device__ __forceinline__ float bf2f(unsigned short h) {
    union { unsigned int u; float f; } c;
    c.u = ((unsigned int)h) << 16;
    return c.f;
}
__device__ __forceinline__ unsigned short f2bf(float f) {
    __hip_bfloat16 h = __float2bfloat16(f);
    return *reinterpret_cast<unsigned short*>(&h);
}

// ---------------------------------------------------------------------------
// K0a: conv_w (640x512 f32) -> bf16 MFMA A-fragment order.
// frag f = (o>>4)*16 + (c>>5); lane = (o&15) | (((c>>3)&3)<<4); elem = c&7.
// Fragment stride = 512 u16.
// ---------------------------------------------------------------------------
__global__ __launch_bounds__(256) void k0_wconv(
    const float* __restrict__ w, unsigned short* __restrict__ wf)
{
    int t = blockIdx.x * 256 + threadIdx.x;       // 0..40959
    int o  = t >> 6;
    int c0 = (t & 63) * 8;
    const float* src = w + (size_t)o * C_ + c0;
    u16x8 p;
#pragma unroll
    for (int e = 0; e < 8; ++e) p[e] = f2bf(src[e]);
    int f = (o >> 4) * 16 + (c0 >> 5);
    int l = (o & 15) | (((c0 >> 3) & 3) << 4);
    *reinterpret_cast<u16x8*>(&wf[(size_t)f * 512 + l * 8]) = p;
}

// ---------------------------------------------------------------------------
// K0b: per-h precomputed B/A fragment tables for K2.
// relB[h][uf=8][lane=64][e=8]: B[s,u]: s<8 -> s_qr*rq[s,u]; 8..15 -> s_kr*rk;
//                              s>=16 or u==127 -> 0.
// relvA[h][if=4][t=4][lane=64][e=8]: A[i, u-slot] = sc_kv(h,i)*relv[i,u].
// ---------------------------------------------------------------------------
__global__ __launch_bounds__(256) void k0_tables(
    const float* __restrict__ rel,
    const float* __restrict__ g2, const float* __restrict__ v2,
    const float* __restrict__ g3, const float* __restrict__ v3,
    unsigned short* __restrict__ relB, unsigned short* __restrict__ relvA)
{
    int tid = blockIdx.x * 256 + threadIdx.x;
    if (tid < 4096) {                      // relB
        int h = tid >> 9, uf = (tid >> 6) & 7, l = tid & 63;
        int u = uf * 16 + (l & 15);
        int g = l >> 4;
        float sq = g2[3*h]     * rsqrtf(v2[3*h]     + EPS_);
        float sk = g2[3*h + 1] * rsqrtf(v2[3*h + 1] + EPS_);
        u16x8 p;
#pragma unroll
        for (int e = 0; e < 8; ++e) {
            int s = g * 8 + e;
            float val = 0.f;
            if (u < 127 && s < 16)
                val = (s < 8 ? sq : sk) * rel[s * 127 + u];
            p[e] = f2bf(val);
        }
        *reinterpret_cast<u16x8*>(&relB[(size_t)tid * 8]) = p;
    } else if (tid < 4096 + 8192) {        // relvA
        int t2 = tid - 4096;
        int h = t2 >> 10, iF = (t2 >> 8) & 3, tt = (t2 >> 6) & 3, l = t2 & 63;
        int i = iF * 16 + (l & 15);
        int c3 = h * 64 + i;
        float scl = g3[c3] * rsqrtf(v3[c3] + EPS_);
        const float* rrow = rel + (size_t)(16 + i) * 127;
        u16x8 p;
#pragma unroll
        for (int e = 0; e < 8; ++e) {
            int u = (l >> 4) * 8 + e + 32 * tt;
            p[e] = f2bf((u < 127) ? scl * rrow[u] : 0.f);
        }
        *reinterpret_cast<u16x8*>(&relvA[(size_t)t2 * 8]) = p;
    }
}

// ---------------------------------------------------------------------------
// K1: qkv[b,o,d] = BN1( sum_c conv_w[o,c]*x[b,c,d] ), d-split (one x read).
// q,k channels -> qkA fragments [b][h][mf=4][lane=64][e=8] bf16
//   (lanes 0..15: q k-slots 0..7; lanes 16..31: k k-slots 8..15; 32..63: 0)
// v channels  -> vB [b][h][i=64][j=64] bf16, pre-scaled by BN3 sc_o.
// 512 thr = 8 waves; block = (b, d-half); wave: 80 o-rows x 32 d.
// ---------------------------------------------------------------------------
#define LDW1 40

__global__ __launch_bounds__(512) void k1_gemm(
    const float* __restrict__ x, const unsigned short* __restrict__ wf,
    const float* __restrict__ g1, const float* __restrict__ b1,
    const float* __restrict__ m1, const float* __restrict__ v1,
    const float* __restrict__ g3, const float* __restrict__ v3,
    unsigned short* __restrict__ qkA, unsigned short* __restrict__ vB)
{
    __shared__ unsigned short xt[32 * LDW1];   // 2560 B
    __shared__ float ssc[640], ssh[640];

    const int tid = threadIdx.x;
    const int b   = blockIdx.x >> 1;
    const int dh  = blockIdx.x & 1;
    const int d0  = dh * 32;

    for (int t = tid; t < 640; t += 512) {
        float sc = g1[t] * rsqrtf(v1[t] + EPS_);
        float sh = b1[t] - m1[t] * sc;
        int cc = t >> 3, hh = t & 7;
        if (cc >= 16) {                        // fold BN3 sc_o into v
            int c3 = 512 + hh * 64 + (cc - 16);
            float f = g3[c3] * rsqrtf(v3[c3] + EPS_);
            sc *= f; sh *= f;
        }
        ssc[t] = sc;
        ssh[t] = sh;
    }

    const int lane = tid & 63;
    const int wv   = tid >> 6;        // 0..7
    const int wrow = wv * 80;
    const int lm   = lane & 15;
    const int lk   = (lane >> 4) * 8;

    f32x4 acc[5][2];
#pragma unroll
    for (int i = 0; i < 5; ++i)
#pragma unroll
        for (int j = 0; j < 2; ++j) acc[i][j] = (f32x4){0.f, 0.f, 0.f, 0.f};

    const float* xb = x + (size_t)b * C_ * D_;
    const int skp = tid >> 5;          // staging k-pair 0..15
    const int sdd = tid & 31;          // staging local d

    for (int kk = 0; kk < C_; kk += 32) {
        __syncthreads();
        bf16x8 af[5];
#pragma unroll
        for (int fm = 0; fm < 5; ++fm) {
            size_t f = (size_t)((wv * 5 + fm) * 16 + (kk >> 5)) * 512;
            af[fm] = *reinterpret_cast<const bf16x8*>(&wf[f + lane * 8]);
        }
        {
            float a0 = xb[(kk + 2 * skp) * 64 + d0 + sdd];
            float a1 = xb[(kk + 2 * skp + 1) * 64 + d0 + sdd];
            unsigned int pk = (unsigned int)f2bf(a0) | ((unsigned int)f2bf(a1) << 16);
            *reinterpret_cast<unsigned int*>(&xt[sdd * LDW1 + 2 * skp]) = pk;
        }
        __syncthreads();

        bf16x8 bfr[2];
#pragma unroll
        for (int fn = 0; fn < 2; ++fn)
            bfr[fn] = *reinterpret_cast<const bf16x8*>(&xt[(fn * 16 + lm) * LDW1 + lk]);
#pragma unroll
        for (int fm = 0; fm < 5; ++fm)
#pragma unroll
            for (int fn = 0; fn < 2; ++fn)
                acc[fm][fn] = __builtin_amdgcn_mfma_f32_16x16x32_bf16(
                    af[fm], bfr[fn], acc[fm][fn], 0, 0, 0);
    }

    const int r0 = (lane >> 4) * 4;
#pragma unroll
    for (int fm = 0; fm < 5; ++fm) {
#pragma unroll
        for (int fn = 0; fn < 2; ++fn) {
            int d = d0 + fn * 16 + lm;
#pragma unroll
            for (int r = 0; r < 4; ++r) {
                int o = wrow + fm * 16 + r0 + r;
                int cc = o >> 3, hh = o & 7;
                float val = acc[fm][fn][r] * ssc[o] + ssh[o];
                unsigned short bv = f2bf(val);
                if (cc < 8)
                    qkA[(((size_t)b * 8 + hh) * 4 + (d >> 4)) * 512 + (d & 15) * 8 + cc] = bv;
                else if (cc < 16)
                    qkA[(((size_t)b * 8 + hh) * 4 + (d >> 4)) * 512 + ((d & 15) + 16) * 8 + (cc - 8)] = bv;
                else
                    vB[((size_t)(b * 8 + hh) * 64 + (cc - 16)) * 64 + d] = bv;
            }
        }
    }
    // zero qkA lanes 32..63 for this block's fragments (MFMA upper-K zeros)
    for (int z = tid; z < 2048; z += 512) {
        int hm  = z >> 7;             // 0..15
        int off = z & 127;
        int hh  = hm >> 1;
        int mf  = dh * 2 + (hm & 1);
        unsigned int* p = reinterpret_cast<unsigned int*>(
            qkA + (((size_t)b * 8 + hh) * 4 + mf) * 512 + 256);
        p[off] = 0u;
    }
}

// ---------------------------------------------------------------------------
// K2: per (b,h): phase1 MFMA scores (dots + full-u SG), phase2 in-reg softmax
//     with f32 band-stored SG gather, phase3 MFMA (out + kv).
// SGb[d][t] = SG[d][u] with t = u - d + 15, t in [0,79): exactly the band
// phase 2 reads (u = d - lmm + {15,31,47,63}). f32 keeps score precision.
// ---------------------------------------------------------------------------
#define SGP 84    // SGb row stride (f32): 336 B == 16 banks mod 32 -> 2-way
#define SA  72    // attn row stride (u16), 16B-aligned
#define RLD 136   // A2 row stride (u16), 16B-aligned

__global__ __launch_bounds__(256) void k2_attn(
    const unsigned short* __restrict__ qkA, const unsigned short* __restrict__ vB,
    const unsigned short* __restrict__ relB, const unsigned short* __restrict__ relvA,
    const float* __restrict__ g2, const float* __restrict__ v2,
    const float* __restrict__ g3, const float* __restrict__ b3,
    const float* __restrict__ m3, const float* __restrict__ v3,
    float* __restrict__ outp)
{
    __shared__ float          SGb[64 * SGP];   // 21504 B
    __shared__ unsigned short attn[64 * SA];   // 9216 B
    __shared__ unsigned short A2[64 * RLD];    // 17408 B
    __shared__ float sh3[64];

    const int tid  = threadIdx.x;
    const int b    = blockIdx.x >> 3;
    const int h    = blockIdx.x & 7;
    const int lane = tid & 63;
    const int w    = tid >> 6;
    const int lmm  = lane & 15;
    const int lg   = lane >> 4;

    const unsigned short* qbase = qkA + ((size_t)(b * 8 + h) * 4) * 512;

    for (int i = tid; i < 64 * RLD / 2; i += 256)
        reinterpret_cast<unsigned int*>(A2)[i] = 0u;
    if (tid < 64) {
        int c = h * 64 + tid;
        float sa = g3[c] * rsqrtf(v3[c] + EPS_);
        float sb = g3[512 + c] * rsqrtf(v3[512 + c] + EPS_);
        sh3[tid] = (b3[c] - m3[c] * sa) + (b3[512 + c] - m3[512 + c] * sb);
    }
    const float s_dt = g2[3 * h + 2] * rsqrtf(v2[3 * h + 2] + EPS_);

    // ---- phase 1: MFMA scores ----
    bf16x8 aA = *reinterpret_cast<const bf16x8*>(&qbase[w * 512 + lane * 8]);
    bf16x8 zv = {0, 0, 0, 0, 0, 0, 0, 0};
    bf16x8 kBf[4];
#pragma unroll
    for (int jf = 0; jf < 4; ++jf) {
        kBf[jf] = zv;
        if (lane < 16)
            kBf[jf] = *reinterpret_cast<const bf16x8*>(&qbase[jf * 512 + (lane + 16) * 8]);
    }
    bf16x8 rBf[8];
#pragma unroll
    for (int uf = 0; uf < 8; ++uf)
        rBf[uf] = *reinterpret_cast<const bf16x8*>(&relB[(size_t)(h * 8 + uf) * 512 + lane * 8]);

    f32x4 dotsAcc[4];
#pragma unroll
    for (int jf = 0; jf < 4; ++jf)
        dotsAcc[jf] = __builtin_amdgcn_mfma_f32_16x16x32_bf16(
            aA, kBf[jf], (f32x4){0.f, 0.f, 0.f, 0.f}, 0, 0, 0);
    f32x4 sgAcc[8];
#pragma unroll
    for (int uf = 0; uf < 8; ++uf)
        sgAcc[uf] = __builtin_amdgcn_mfma_f32_16x16x32_bf16(
            aA, rBf[uf], (f32x4){0.f, 0.f, 0.f, 0.f}, 0, 0, 0);

    // write SGb (f32 band): row d = w*16 + lg*4 + r, t = u - d + 15
#pragma unroll
    for (int uf = 0; uf < 8; ++uf) {
#pragma unroll
        for (int r = 0; r < 4; ++r) {
            int d = (w << 4) + (lg << 2) + r;
            int t = uf * 16 + lmm - d + 15;
            if (t >= 0 && t < 79)
                SGb[d * SGP + t] = sgAcc[uf][r];
        }
    }
    __syncthreads();

    // ---- phase 2: softmax (row d across 16 lanes of the lg-group) ----
#pragma unroll
    for (int r = 0; r < 4; ++r) {
        int d = (w << 4) + (lg << 2) + r;
        const float* sgr = &SGb[d * SGP];
        float sc0 = s_dt * dotsAcc[0][r] + sgr[78 - lmm];
        float sc1 = s_dt * dotsAcc[1][r] + sgr[62 - lmm];
        float sc2 = s_dt * dotsAcc[2][r] + sgr[46 - lmm];
        float sc3 = s_dt * dotsAcc[3][r] + sgr[30 - lmm];
        float mx = fmaxf(fmaxf(sc0, sc1), fmaxf(sc2, sc3));
        mx = fmaxf(mx, __shfl_xor(mx, 1));
        mx = fmaxf(mx, __shfl_xor(mx, 2));
        mx = fmaxf(mx, __shfl_xor(mx, 4));
        mx = fmaxf(mx, __shfl_xor(mx, 8));
        float e0 = __expf(sc0 - mx), e1 = __expf(sc1 - mx);
        float e2 = __expf(sc2 - mx), e3 = __expf(sc3 - mx);
        float sum = (e0 + e1) + (e2 + e3);
        sum += __shfl_xor(sum, 1);
        sum += __shfl_xor(sum, 2);
        sum += __shfl_xor(sum, 4);
        sum += __shfl_xor(sum, 8);
        float inv = 1.f / sum;
        unsigned short p0 = f2bf(e0 * inv), p1 = f2bf(e1 * inv);
        unsigned short p2 = f2bf(e2 * inv), p3 = f2bf(e3 * inv);
        attn[d * SA + lmm]      = p0;
        attn[d * SA + 16 + lmm] = p1;
        attn[d * SA + 32 + lmm] = p2;
        attn[d * SA + 48 + lmm] = p3;
        A2[d * RLD + 63 + d - lmm] = p0;
        A2[d * RLD + 47 + d - lmm] = p1;
        A2[d * RLD + 31 + d - lmm] = p2;
        A2[d * RLD + 15 + d - lmm] = p3;
    }

    // ---- phase-3 A-fragment loads (global; land during barrier) ----
    const int lk8  = lg * 8;
    const int irow = (w << 4) + lmm;
    const unsigned short* vbase = vB + (size_t)(b * 8 + h) * 4096;
    bf16x8 av0 = *reinterpret_cast<const bf16x8*>(&vbase[irow * 64 + lk8]);
    bf16x8 av1 = *reinterpret_cast<const bf16x8*>(&vbase[irow * 64 + 32 + lk8]);
    bf16x8 rvA[4];
#pragma unroll
    for (int t = 0; t < 4; ++t)
        rvA[t] = *reinterpret_cast<const bf16x8*>(
            &relvA[(size_t)(((h * 4 + w) * 4 + t)) * 512 + lane * 8]);

    __syncthreads();

    // ---- phase 3: MFMA out + kv ----
    f32x4 acc[4];
#pragma unroll
    for (int nf = 0; nf < 4; ++nf) acc[nf] = (f32x4){0.f, 0.f, 0.f, 0.f};

#pragma unroll
    for (int nf = 0; nf < 4; ++nf) {
        const unsigned short* arow = &attn[(nf * 16 + lmm) * SA + lk8];
        acc[nf] = __builtin_amdgcn_mfma_f32_16x16x32_bf16(
            av0, *reinterpret_cast<const bf16x8*>(&arow[0]), acc[nf], 0, 0, 0);
        acc[nf] = __builtin_amdgcn_mfma_f32_16x16x32_bf16(
            av1, *reinterpret_cast<const bf16x8*>(&arow[32]), acc[nf], 0, 0, 0);
        const unsigned short* a2row = &A2[(nf * 16 + lmm) * RLD + lk8];
        acc[nf] = __builtin_amdgcn_mfma_f32_16x16x32_bf16(
            rvA[0], *reinterpret_cast<const bf16x8*>(&a2row[0]), acc[nf], 0, 0, 0);
        acc[nf] = __builtin_amdgcn_mfma_f32_16x16x32_bf16(
            rvA[1], *reinterpret_cast<const bf16x8*>(&a2row[32]), acc[nf], 0, 0, 0);
        acc[nf] = __builtin_amdgcn_mfma_f32_16x16x32_bf16(
            rvA[2], *reinterpret_cast<const bf16x8*>(&a2row[64]), acc[nf], 0, 0, 0);
        acc[nf] = __builtin_amdgcn_mfma_f32_16x16x32_bf16(
            rvA[3], *reinterpret_cast<const bf16x8*>(&a2row[96]), acc[nf], 0, 0, 0);
    }

    // ---- epilogue ----
    float* op = outp + ((size_t)b * 512 + h * 64) * 64;
    const int r0 = lg * 4;
#pragma unroll
    for (int r = 0; r < 4; ++r) {
        int i = (w << 4) + r0 + r;
        float sh = sh3[i];
#pragma unroll
        for (int nf = 0; nf < 4; ++nf)
            op[(size_t)i * 64 + nf * 16 + lmm] = acc[nf][r] + sh;
    }
}

extern "C" void kernel_launch(void* const* d_in, const int* in_sizes, int n_in,
                              void* d_out, int out_size, void* d_ws, size_t ws_size,
                              hipStream_t stream) {
    (void)in_sizes; (void)n_in; (void)out_size; (void)ws_size;
    const float* x   = (const float*)d_in[0];
    const float* w   = (const float*)d_in[1];
    const float* g1  = (const float*)d_in[2];
    const float* b1  = (const float*)d_in[3];
    const float* m1  = (const float*)d_in[4];
    const float* v1  = (const float*)d_in[5];
    const float* rel = (const float*)d_in[6];
    const float* g2  = (const float*)d_in[7];
    const float* b2  = (const float*)d_in[8];  (void)b2;
    const float* m2  = (const float*)d_in[9];  (void)m2;
    const float* v2  = (const float*)d_in[10];
    const float* g3  = (const float*)d_in[11];
    const float* b3  = (const float*)d_in[12];
    const float* m3  = (const float*)d_in[13];
    const float* v3  = (const float*)d_in[14];
    float* out = (float*)d_out;

    // ws: wf 640KB | relB 64KB | relvA 128KB | pad | qkA 32MB | vB 64MB
    unsigned short* wfrag = (unsigned short*)d_ws;
    unsigned short* relB  = (unsigned short*)((char*)d_ws + 655360);
    unsigned short* relvA = (unsigned short*)((char*)d_ws + 720896);
    unsigned short* qkA   = (unsigned short*)((char*)d_ws + 1048576);
    unsigned short* vB    = (unsigned short*)((char*)d_ws + 1048576 + (size_t)33554432);

    hipLaunchKernelGGL(k0_wconv, dim3(160), dim3(256), 0, stream, w, wfrag);
    hipLaunchKernelGGL(k0_tables, dim3(48), dim3(256), 0, stream,
                       rel, g2, v2, g3, v3, relB, relvA);
    hipLaunchKernelGGL(k1_gemm, dim3(2048), dim3(512), 0, stream,
                       x, wfrag, g1, b1, m1, v1, g3, v3, qkA, vB);
    hipLaunchKernelGGL(k2_attn, dim3(8192), dim3(256), 0, stream,
                       qkA, vB, relB, relvA, g2, v2, g3, b3, m3, v3, out);
}

// Round 7
// 192.104 us; speedup vs baseline: 3.1063x; 1.0586x over previous
//
#include <hip/hip_runtime.h>
#include <hip/hip_bf16.h>

#define B_    1024
#define C_    512
#define H_    8
#define D_    64
#define EPS_  1e-5f

typedef __attribute__((ext_vector_type(4))) float f32x4;
typedef __attribute__((ext_vector_type(8))) short bf16x8;
typedef __attribute__((ext_vector_type(8))) unsigned short u16x8;

__device__ __forceinline__ float bf2f(unsigned short h) {
    union { unsigned int u; float f; } c;
    c.u = ((unsigned int)h) << 16;
    return c.f;
}
__device__ __forceinline__ unsigned short f2bf(float f) {
    __hip_bfloat16 h = __float2bfloat16(f);
    return *reinterpret_cast<unsigned short*>(&h);
}

// ---------------------------------------------------------------------------
// K0a: conv_w (640x512 f32) -> bf16 MFMA A-fragment order.
// frag f = (o>>4)*16 + (c>>5); lane = (o&15) | (((c>>3)&3)<<4); elem = c&7.
// Fragment stride = 512 u16.
// ---------------------------------------------------------------------------
__global__ __launch_bounds__(256) void k0_wconv(
    const float* __restrict__ w, unsigned short* __restrict__ wf)
{
    int t = blockIdx.x * 256 + threadIdx.x;       // 0..40959
    int o  = t >> 6;
    int c0 = (t & 63) * 8;
    const float* src = w + (size_t)o * C_ + c0;
    u16x8 p;
#pragma unroll
    for (int e = 0; e < 8; ++e) p[e] = f2bf(src[e]);
    int f = (o >> 4) * 16 + (c0 >> 5);
    int l = (o & 15) | (((c0 >> 3) & 3) << 4);
    *reinterpret_cast<u16x8*>(&wf[(size_t)f * 512 + l * 8]) = p;
}

// ---------------------------------------------------------------------------
// K0b: per-h precomputed B/A fragment tables for K2 (unchanged).
// ---------------------------------------------------------------------------
__global__ __launch_bounds__(256) void k0_tables(
    const float* __restrict__ rel,
    const float* __restrict__ g2, const float* __restrict__ v2,
    const float* __restrict__ g3, const float* __restrict__ v3,
    unsigned short* __restrict__ relB, unsigned short* __restrict__ relvA)
{
    int tid = blockIdx.x * 256 + threadIdx.x;
    if (tid < 4096) {                      // relB
        int h = tid >> 9, uf = (tid >> 6) & 7, l = tid & 63;
        int u = uf * 16 + (l & 15);
        int g = l >> 4;
        float sq = g2[3*h]     * rsqrtf(v2[3*h]     + EPS_);
        float sk = g2[3*h + 1] * rsqrtf(v2[3*h + 1] + EPS_);
        u16x8 p;
#pragma unroll
        for (int e = 0; e < 8; ++e) {
            int s = g * 8 + e;
            float val = 0.f;
            if (u < 127 && s < 16)
                val = (s < 8 ? sq : sk) * rel[s * 127 + u];
            p[e] = f2bf(val);
        }
        *reinterpret_cast<u16x8*>(&relB[(size_t)tid * 8]) = p;
    } else if (tid < 4096 + 8192) {        // relvA
        int t2 = tid - 4096;
        int h = t2 >> 10, iF = (t2 >> 8) & 3, tt = (t2 >> 6) & 3, l = t2 & 63;
        int i = iF * 16 + (l & 15);
        int c3 = h * 64 + i;
        float scl = g3[c3] * rsqrtf(v3[c3] + EPS_);
        const float* rrow = rel + (size_t)(16 + i) * 127;
        u16x8 p;
#pragma unroll
        for (int e = 0; e < 8; ++e) {
            int u = (l >> 4) * 8 + e + 32 * tt;
            p[e] = f2bf((u < 127) ? scl * rrow[u] : 0.f);
        }
        *reinterpret_cast<u16x8*>(&relvA[(size_t)t2 * 8]) = p;
    }
}

// ---------------------------------------------------------------------------
// K1 v2: one block per b, M=640 x N=64 x K=512. BK=64, double-buffered LDS,
// ONE barrier per K-step (8 total). A-frags stream from L2-resident wf.
// Wave wv: 80 o-rows (5 frags) x 64 d (4 frags); 40 MFMA per K-step.
// ---------------------------------------------------------------------------
#define LDW1 72   // bf16 row stride: 144 B; frag reads 2-way bank (free)

__global__ __launch_bounds__(512) void k1_gemm(
    const float* __restrict__ x, const unsigned short* __restrict__ wf,
    const float* __restrict__ g1, const float* __restrict__ b1,
    const float* __restrict__ m1, const float* __restrict__ v1,
    const float* __restrict__ g3, const float* __restrict__ v3,
    unsigned short* __restrict__ qkA, unsigned short* __restrict__ vB)
{
    __shared__ unsigned short xt[2][64 * LDW1];   // 2 x 9216 B
    __shared__ float ssc[640], ssh[640];

    const int tid = threadIdx.x;
    const int b   = blockIdx.x;

    for (int t = tid; t < 640; t += 512) {
        float sc = g1[t] * rsqrtf(v1[t] + EPS_);
        float sh = b1[t] - m1[t] * sc;
        int cc = t >> 3, hh = t & 7;
        if (cc >= 16) {                        // fold BN3 sc_o into v
            int c3 = 512 + hh * 64 + (cc - 16);
            float f = g3[c3] * rsqrtf(v3[c3] + EPS_);
            sc *= f; sh *= f;
        }
        ssc[t] = sc;
        ssh[t] = sh;
    }

    const int lane = tid & 63;
    const int wv   = tid >> 6;        // 0..7
    const int lm   = lane & 15;
    const int lg   = lane >> 4;

    const float* xb = x + (size_t)b * C_ * D_;
    const int cp = tid >> 4;          // c-pair 0..31
    const int c4 = (tid & 15) * 4;    // d col 0,4,..,60

    f32x4 acc[5][4];
#pragma unroll
    for (int i = 0; i < 5; ++i)
#pragma unroll
        for (int j = 0; j < 4; ++j) acc[i][j] = (f32x4){0.f, 0.f, 0.f, 0.f};

    // prologue: stage tile 0 into buf 0
    {
        f32x4 a = *reinterpret_cast<const f32x4*>(&xb[(2 * cp) * 64 + c4]);
        f32x4 c = *reinterpret_cast<const f32x4*>(&xb[(2 * cp + 1) * 64 + c4]);
#pragma unroll
        for (int j = 0; j < 4; ++j) {
            unsigned int pk = (unsigned int)f2bf(a[j]) | ((unsigned int)f2bf(c[j]) << 16);
            *reinterpret_cast<unsigned int*>(&xt[0][(c4 + j) * LDW1 + 2 * cp]) = pk;
        }
    }
    __syncthreads();

    int cur = 0;
    for (int kt = 0; kt < 8; ++kt) {
        // prefetch next x tile into registers (overlaps MFMA cluster)
        f32x4 pa, pc;
        if (kt < 7) {
            pa = *reinterpret_cast<const f32x4*>(&xb[((kt + 1) * 64 + 2 * cp) * 64 + c4]);
            pc = *reinterpret_cast<const f32x4*>(&xb[((kt + 1) * 64 + 2 * cp + 1) * 64 + c4]);
        }
#pragma unroll
        for (int ks = 0; ks < 2; ++ks) {
            bf16x8 af[5];
#pragma unroll
            for (int fm = 0; fm < 5; ++fm) {
                size_t f = (size_t)((wv * 5 + fm) * 16 + kt * 2 + ks) * 512;
                af[fm] = *reinterpret_cast<const bf16x8*>(&wf[f + lane * 8]);
            }
            bf16x8 bfr[4];
#pragma unroll
            for (int fn = 0; fn < 4; ++fn)
                bfr[fn] = *reinterpret_cast<const bf16x8*>(
                    &xt[cur][(fn * 16 + lm) * LDW1 + ks * 32 + lg * 8]);
#pragma unroll
            for (int fm = 0; fm < 5; ++fm)
#pragma unroll
                for (int fn = 0; fn < 4; ++fn)
                    acc[fm][fn] = __builtin_amdgcn_mfma_f32_16x16x32_bf16(
                        af[fm], bfr[fn], acc[fm][fn], 0, 0, 0);
        }
        if (kt < 7) {
#pragma unroll
            for (int j = 0; j < 4; ++j) {
                unsigned int pk = (unsigned int)f2bf(pa[j]) | ((unsigned int)f2bf(pc[j]) << 16);
                *reinterpret_cast<unsigned int*>(&xt[cur ^ 1][(c4 + j) * LDW1 + 2 * cp]) = pk;
            }
        }
        __syncthreads();
        cur ^= 1;
    }

    // epilogue: BN1 (+folded BN3 for v) and scatter
#pragma unroll
    for (int fm = 0; fm < 5; ++fm) {
#pragma unroll
        for (int fn = 0; fn < 4; ++fn) {
            int d = fn * 16 + lm;
#pragma unroll
            for (int r = 0; r < 4; ++r) {
                int o = wv * 80 + fm * 16 + lg * 4 + r;
                int cc = o >> 3, hh = o & 7;
                float val = acc[fm][fn][r] * ssc[o] + ssh[o];
                unsigned short bv = f2bf(val);
                if (cc < 8)
                    qkA[(((size_t)b * 8 + hh) * 4 + (d >> 4)) * 512 + (d & 15) * 8 + cc] = bv;
                else if (cc < 16)
                    qkA[(((size_t)b * 8 + hh) * 4 + (d >> 4)) * 512 + ((d & 15) + 16) * 8 + (cc - 8)] = bv;
                else
                    vB[((size_t)(b * 8 + hh) * 64 + (cc - 16)) * 64 + d] = bv;
            }
        }
    }
    // zero qkA lanes 32..63 (MFMA upper-K zeros): 8 hh x 4 mf x 128 u32
    for (int z = tid; z < 4096; z += 512) {
        int hh  = z >> 9;
        int mf  = (z >> 7) & 3;
        int off = z & 127;
        unsigned int* p = reinterpret_cast<unsigned int*>(
            qkA + (((size_t)b * 8 + hh) * 4 + mf) * 512 + 256);
        p[off] = 0u;
    }
}

// ---------------------------------------------------------------------------
// K2: unchanged from round 6 (validated).
// ---------------------------------------------------------------------------
#define SGP 84    // SGb row stride (f32)
#define SA  72    // attn row stride (u16)
#define RLD 136   // A2 row stride (u16)

__global__ __launch_bounds__(256) void k2_attn(
    const unsigned short* __restrict__ qkA, const unsigned short* __restrict__ vB,
    const unsigned short* __restrict__ relB, const unsigned short* __restrict__ relvA,
    const float* __restrict__ g2, const float* __restrict__ v2,
    const float* __restrict__ g3, const float* __restrict__ b3,
    const float* __restrict__ m3, const float* __restrict__ v3,
    float* __restrict__ outp)
{
    __shared__ float          SGb[64 * SGP];   // 21504 B
    __shared__ unsigned short attn[64 * SA];   // 9216 B
    __shared__ unsigned short A2[64 * RLD];    // 17408 B
    __shared__ float sh3[64];

    const int tid  = threadIdx.x;
    const int b    = blockIdx.x >> 3;
    const int h    = blockIdx.x & 7;
    const int lane = tid & 63;
    const int w    = tid >> 6;
    const int lmm  = lane & 15;
    const int lg   = lane >> 4;

    const unsigned short* qbase = qkA + ((size_t)(b * 8 + h) * 4) * 512;

    for (int i = tid; i < 64 * RLD / 2; i += 256)
        reinterpret_cast<unsigned int*>(A2)[i] = 0u;
    if (tid < 64) {
        int c = h * 64 + tid;
        float sa = g3[c] * rsqrtf(v3[c] + EPS_);
        float sb = g3[512 + c] * rsqrtf(v3[512 + c] + EPS_);
        sh3[tid] = (b3[c] - m3[c] * sa) + (b3[512 + c] - m3[512 + c] * sb);
    }
    const float s_dt = g2[3 * h + 2] * rsqrtf(v2[3 * h + 2] + EPS_);

    // ---- phase 1: MFMA scores ----
    bf16x8 aA = *reinterpret_cast<const bf16x8*>(&qbase[w * 512 + lane * 8]);
    bf16x8 zv = {0, 0, 0, 0, 0, 0, 0, 0};
    bf16x8 kBf[4];
#pragma unroll
    for (int jf = 0; jf < 4; ++jf) {
        kBf[jf] = zv;
        if (lane < 16)
            kBf[jf] = *reinterpret_cast<const bf16x8*>(&qbase[jf * 512 + (lane + 16) * 8]);
    }
    bf16x8 rBf[8];
#pragma unroll
    for (int uf = 0; uf < 8; ++uf)
        rBf[uf] = *reinterpret_cast<const bf16x8*>(&relB[(size_t)(h * 8 + uf) * 512 + lane * 8]);

    f32x4 dotsAcc[4];
#pragma unroll
    for (int jf = 0; jf < 4; ++jf)
        dotsAcc[jf] = __builtin_amdgcn_mfma_f32_16x16x32_bf16(
            aA, kBf[jf], (f32x4){0.f, 0.f, 0.f, 0.f}, 0, 0, 0);
    f32x4 sgAcc[8];
#pragma unroll
    for (int uf = 0; uf < 8; ++uf)
        sgAcc[uf] = __builtin_amdgcn_mfma_f32_16x16x32_bf16(
            aA, rBf[uf], (f32x4){0.f, 0.f, 0.f, 0.f}, 0, 0, 0);

    // write SGb (f32 band): row d = w*16 + lg*4 + r, t = u - d + 15
#pragma unroll
    for (int uf = 0; uf < 8; ++uf) {
#pragma unroll
        for (int r = 0; r < 4; ++r) {
            int d = (w << 4) + (lg << 2) + r;
            int t = uf * 16 + lmm - d + 15;
            if (t >= 0 && t < 79)
                SGb[d * SGP + t] = sgAcc[uf][r];
        }
    }
    __syncthreads();

    // ---- phase 2: softmax (row d across 16 lanes of the lg-group) ----
#pragma unroll
    for (int r = 0; r < 4; ++r) {
        int d = (w << 4) + (lg << 2) + r;
        const float* sgr = &SGb[d * SGP];
        float sc0 = s_dt * dotsAcc[0][r] + sgr[78 - lmm];
        float sc1 = s_dt * dotsAcc[1][r] + sgr[62 - lmm];
        float sc2 = s_dt * dotsAcc[2][r] + sgr[46 - lmm];
        float sc3 = s_dt * dotsAcc[3][r] + sgr[30 - lmm];
        float mx = fmaxf(fmaxf(sc0, sc1), fmaxf(sc2, sc3));
        mx = fmaxf(mx, __shfl_xor(mx, 1));
        mx = fmaxf(mx, __shfl_xor(mx, 2));
        mx = fmaxf(mx, __shfl_xor(mx, 4));
        mx = fmaxf(mx, __shfl_xor(mx, 8));
        float e0 = __expf(sc0 - mx), e1 = __expf(sc1 - mx);
        float e2 = __expf(sc2 - mx), e3 = __expf(sc3 - mx);
        float sum = (e0 + e1) + (e2 + e3);
        sum += __shfl_xor(sum, 1);
        sum += __shfl_xor(sum, 2);
        sum += __shfl_xor(sum, 4);
        sum += __shfl_xor(sum, 8);
        float inv = 1.f / sum;
        unsigned short p0 = f2bf(e0 * inv), p1 = f2bf(e1 * inv);
        unsigned short p2 = f2bf(e2 * inv), p3 = f2bf(e3 * inv);
        attn[d * SA + lmm]      = p0;
        attn[d * SA + 16 + lmm] = p1;
        attn[d * SA + 32 + lmm] = p2;
        attn[d * SA + 48 + lmm] = p3;
        A2[d * RLD + 63 + d - lmm] = p0;
        A2[d * RLD + 47 + d - lmm] = p1;
        A2[d * RLD + 31 + d - lmm] = p2;
        A2[d * RLD + 15 + d - lmm] = p3;
    }

    // ---- phase-3 A-fragment loads (global; land during barrier) ----
    const int lk8  = lg * 8;
    const int irow = (w << 4) + lmm;
    const unsigned short* vbase = vB + (size_t)(b * 8 + h) * 4096;
    bf16x8 av0 = *reinterpret_cast<const bf16x8*>(&vbase[irow * 64 + lk8]);
    bf16x8 av1 = *reinterpret_cast<const bf16x8*>(&vbase[irow * 64 + 32 + lk8]);
    bf16x8 rvA[4];
#pragma unroll
    for (int t = 0; t < 4; ++t)
        rvA[t] = *reinterpret_cast<const bf16x8*>(
            &relvA[(size_t)(((h * 4 + w) * 4 + t)) * 512 + lane * 8]);

    __syncthreads();

    // ---- phase 3: MFMA out + kv ----
    f32x4 acc[4];
#pragma unroll
    for (int nf = 0; nf < 4; ++nf) acc[nf] = (f32x4){0.f, 0.f, 0.f, 0.f};

#pragma unroll
    for (int nf = 0; nf < 4; ++nf) {
        const unsigned short* arow = &attn[(nf * 16 + lmm) * SA + lk8];
        acc[nf] = __builtin_amdgcn_mfma_f32_16x16x32_bf16(
            av0, *reinterpret_cast<const bf16x8*>(&arow[0]), acc[nf], 0, 0, 0);
        acc[nf] = __builtin_amdgcn_mfma_f32_16x16x32_bf16(
            av1, *reinterpret_cast<const bf16x8*>(&arow[32]), acc[nf], 0, 0, 0);
        const unsigned short* a2row = &A2[(nf * 16 + lmm) * RLD + lk8];
        acc[nf] = __builtin_amdgcn_mfma_f32_16x16x32_bf16(
            rvA[0], *reinterpret_cast<const bf16x8*>(&a2row[0]), acc[nf], 0, 0, 0);
        acc[nf] = __builtin_amdgcn_mfma_f32_16x16x32_bf16(
            rvA[1], *reinterpret_cast<const bf16x8*>(&a2row[32]), acc[nf], 0, 0, 0);
        acc[nf] = __builtin_amdgcn_mfma_f32_16x16x32_bf16(
            rvA[2], *reinterpret_cast<const bf16x8*>(&a2row[64]), acc[nf], 0, 0, 0);
        acc[nf] = __builtin_amdgcn_mfma_f32_16x16x32_bf16(
            rvA[3], *reinterpret_cast<const bf16x8*>(&a2row[96]), acc[nf], 0, 0, 0);
    }

    // ---- epilogue ----
    float* op = outp + ((size_t)b * 512 + h * 64) * 64;
    const int r0 = lg * 4;
#pragma unroll
    for (int r = 0; r < 4; ++r) {
        int i = (w << 4) + r0 + r;
        float sh = sh3[i];
#pragma unroll
        for (int nf = 0; nf < 4; ++nf)
            op[(size_t)i * 64 + nf * 16 + lmm] = acc[nf][r] + sh;
    }
}

extern "C" void kernel_launch(void* const* d_in, const int* in_sizes, int n_in,
                              void* d_out, int out_size, void* d_ws, size_t ws_size,
                              hipStream_t stream) {
    (void)in_sizes; (void)n_in; (void)out_size; (void)ws_size;
    const float* x   = (const float*)d_in[0];
    const float* w   = (const float*)d_in[1];
    const float* g1  = (const float*)d_in[2];
    const float* b1  = (const float*)d_in[3];
    const float* m1  = (const float*)d_in[4];
    const float* v1  = (const float*)d_in[5];
    const float* rel = (const float*)d_in[6];
    const float* g2  = (const float*)d_in[7];
    const float* b2  = (const float*)d_in[8];  (void)b2;
    const float* m2  = (const float*)d_in[9];  (void)m2;
    const float* v2  = (const float*)d_in[10];
    const float* g3  = (const float*)d_in[11];
    const float* b3  = (const float*)d_in[12];
    const float* m3  = (const float*)d_in[13];
    const float* v3  = (const float*)d_in[14];
    float* out = (float*)d_out;

    // ws: wf 640KB | relB 64KB | relvA 128KB | pad | qkA 32MB | vB 64MB
    unsigned short* wfrag = (unsigned short*)d_ws;
    unsigned short* relB  = (unsigned short*)((char*)d_ws + 655360);
    unsigned short* relvA = (unsigned short*)((char*)d_ws + 720896);
    unsigned short* qkA   = (unsigned short*)((char*)d_ws + 1048576);
    unsigned short* vB    = (unsigned short*)((char*)d_ws + 1048576 + (size_t)33554432);

    hipLaunchKernelGGL(k0_wconv, dim3(160), dim3(256), 0, stream, w, wfrag);
    hipLaunchKernelGGL(k0_tables, dim3(48), dim3(256), 0, stream,
                       rel, g2, v2, g3, v3, relB, relvA);
    hipLaunchKernelGGL(k1_gemm, dim3(1024), dim3(512), 0, stream,
                       x, wfrag, g1, b1, m1, v1, g3, v3, qkA, vB);
    hipLaunchKernelGGL(k2_attn, dim3(8192), dim3(256), 0, stream,
                       qkA, vB, relB, relvA, g2, v2, g3, b3, m3, v3, out);
}

// Round 8
// 168.166 us; speedup vs baseline: 3.5485x; 1.1424x over previous
//
#include <hip/hip_runtime.h>
#include <hip/hip_bf16.h>

#define B_    1024
#define C_    512
#define H_    8
#define D_    64
#define EPS_  1e-5f

typedef __attribute__((ext_vector_type(4))) float f32x4;
typedef __attribute__((ext_vector_type(8))) short bf16x8;
typedef __attribute__((ext_vector_type(8))) unsigned short u16x8;

__device__ __forceinline__ float bf2f(unsigned short h) {
    union { unsigned int u; float f; } c;
    c.u = ((unsigned int)h) << 16;
    return c.f;
}
__device__ __forceinline__ unsigned short f2bf(float f) {
    __hip_bfloat16 h = __float2bfloat16(f);
    return *reinterpret_cast<unsigned short*>(&h);
}

// ---------------------------------------------------------------------------
// K0a: conv_w (640x512 f32) -> bf16 MFMA A-fragment order.
// frag f = (o>>4)*16 + (c>>5); lane = (o&15) | (((c>>3)&3)<<4); elem = c&7.
// Fragment stride = 512 u16.
// ---------------------------------------------------------------------------
__global__ __launch_bounds__(256) void k0_wconv(
    const float* __restrict__ w, unsigned short* __restrict__ wf)
{
    int t = blockIdx.x * 256 + threadIdx.x;       // 0..40959
    int o  = t >> 6;
    int c0 = (t & 63) * 8;
    const float* src = w + (size_t)o * C_ + c0;
    u16x8 p;
#pragma unroll
    for (int e = 0; e < 8; ++e) p[e] = f2bf(src[e]);
    int f = (o >> 4) * 16 + (c0 >> 5);
    int l = (o & 15) | (((c0 >> 3) & 3) << 4);
    *reinterpret_cast<u16x8*>(&wf[(size_t)f * 512 + l * 8]) = p;
}

// ---------------------------------------------------------------------------
// K0b: per-h precomputed B/A fragment tables for K2 (unchanged).
// ---------------------------------------------------------------------------
__global__ __launch_bounds__(256) void k0_tables(
    const float* __restrict__ rel,
    const float* __restrict__ g2, const float* __restrict__ v2,
    const float* __restrict__ g3, const float* __restrict__ v3,
    unsigned short* __restrict__ relB, unsigned short* __restrict__ relvA)
{
    int tid = blockIdx.x * 256 + threadIdx.x;
    if (tid < 4096) {                      // relB
        int h = tid >> 9, uf = (tid >> 6) & 7, l = tid & 63;
        int u = uf * 16 + (l & 15);
        int g = l >> 4;
        float sq = g2[3*h]     * rsqrtf(v2[3*h]     + EPS_);
        float sk = g2[3*h + 1] * rsqrtf(v2[3*h + 1] + EPS_);
        u16x8 p;
#pragma unroll
        for (int e = 0; e < 8; ++e) {
            int s = g * 8 + e;
            float val = 0.f;
            if (u < 127 && s < 16)
                val = (s < 8 ? sq : sk) * rel[s * 127 + u];
            p[e] = f2bf(val);
        }
        *reinterpret_cast<u16x8*>(&relB[(size_t)tid * 8]) = p;
    } else if (tid < 4096 + 8192) {        // relvA
        int t2 = tid - 4096;
        int h = t2 >> 10, iF = (t2 >> 8) & 3, tt = (t2 >> 6) & 3, l = t2 & 63;
        int i = iF * 16 + (l & 15);
        int c3 = h * 64 + i;
        float scl = g3[c3] * rsqrtf(v3[c3] + EPS_);
        const float* rrow = rel + (size_t)(16 + i) * 127;
        u16x8 p;
#pragma unroll
        for (int e = 0; e < 8; ++e) {
            int u = (l >> 4) * 8 + e + 32 * tt;
            p[e] = f2bf((u < 127) ? scl * rrow[u] : 0.f);
        }
        *reinterpret_cast<u16x8*>(&relvA[(size_t)t2 * 8]) = p;
    }
}

// ---------------------------------------------------------------------------
// K1 v3: one block per b, M=640 x N=64 x K=512. BK=64, double-buffered LDS,
// one barrier per K-step, and wf A-fragments software-pipelined ONE FULL
// K-STEP AHEAD in registers (ping-pong afA/afB) so no L2 latency is exposed.
// ---------------------------------------------------------------------------
#define LDW1 72   // bf16 row stride: 144 B

struct K1Ctx {
    const float* xb;
    const unsigned short* wf;
    unsigned short (*xt)[64 * LDW1];
    int wv, lane, lm, lg, cp, c4;
};

template<int KT>
__device__ __forceinline__ void k1_step(const K1Ctx& c, f32x4 (&acc)[5][4],
                                        bf16x8 (&afu)[10], bf16x8 (&afp)[10])
{
    // prefetch next step's wf fragments (registers, used next step)
    if (KT < 7) {
#pragma unroll
        for (int i = 0; i < 10; ++i) {
            int fm = i % 5, ks = i / 5;
            size_t f = (size_t)((c.wv * 5 + fm) * 16 + (KT + 1) * 2 + ks) * 512;
            afp[i] = *reinterpret_cast<const bf16x8*>(&c.wf[f + c.lane * 8]);
        }
    }
    // prefetch next x tile (registers)
    f32x4 pa, pc;
    if (KT < 7) {
        pa = *reinterpret_cast<const f32x4*>(&c.xb[((KT + 1) * 64 + 2 * c.cp) * 64 + c.c4]);
        pc = *reinterpret_cast<const f32x4*>(&c.xb[((KT + 1) * 64 + 2 * c.cp + 1) * 64 + c.c4]);
    }
    // MFMA cluster on current buffers
#pragma unroll
    for (int ks = 0; ks < 2; ++ks) {
        bf16x8 bfr[4];
#pragma unroll
        for (int fn = 0; fn < 4; ++fn)
            bfr[fn] = *reinterpret_cast<const bf16x8*>(
                &c.xt[KT & 1][(fn * 16 + c.lm) * LDW1 + ks * 32 + c.lg * 8]);
#pragma unroll
        for (int fm = 0; fm < 5; ++fm)
#pragma unroll
            for (int fn = 0; fn < 4; ++fn)
                acc[fm][fn] = __builtin_amdgcn_mfma_f32_16x16x32_bf16(
                    afu[ks * 5 + fm], bfr[fn], acc[fm][fn], 0, 0, 0);
    }
    // write next x tile to alternate LDS buffer
    if (KT < 7) {
#pragma unroll
        for (int j = 0; j < 4; ++j) {
            unsigned int pk = (unsigned int)f2bf(pa[j]) | ((unsigned int)f2bf(pc[j]) << 16);
            *reinterpret_cast<unsigned int*>(
                &c.xt[(KT & 1) ^ 1][(c.c4 + j) * LDW1 + 2 * c.cp]) = pk;
        }
    }
    __syncthreads();
}

__global__ __launch_bounds__(512) void k1_gemm(
    const float* __restrict__ x, const unsigned short* __restrict__ wf,
    const float* __restrict__ g1, const float* __restrict__ b1,
    const float* __restrict__ m1, const float* __restrict__ v1,
    const float* __restrict__ g3, const float* __restrict__ v3,
    unsigned short* __restrict__ qkA, unsigned short* __restrict__ vB)
{
    __shared__ unsigned short xt[2][64 * LDW1];   // 2 x 9216 B
    __shared__ float ssc[640], ssh[640];

    const int tid = threadIdx.x;
    const int b   = blockIdx.x;

    for (int t = tid; t < 640; t += 512) {
        float sc = g1[t] * rsqrtf(v1[t] + EPS_);
        float sh = b1[t] - m1[t] * sc;
        int cc = t >> 3, hh = t & 7;
        if (cc >= 16) {                        // fold BN3 sc_o into v
            int c3 = 512 + hh * 64 + (cc - 16);
            float f = g3[c3] * rsqrtf(v3[c3] + EPS_);
            sc *= f; sh *= f;
        }
        ssc[t] = sc;
        ssh[t] = sh;
    }

    K1Ctx c;
    c.xb   = x + (size_t)b * C_ * D_;
    c.wf   = wf;
    c.xt   = xt;
    c.lane = tid & 63;
    c.wv   = tid >> 6;
    c.lm   = c.lane & 15;
    c.lg   = c.lane >> 4;
    c.cp   = tid >> 4;
    c.c4   = (tid & 15) * 4;

    f32x4 acc[5][4];
#pragma unroll
    for (int i = 0; i < 5; ++i)
#pragma unroll
        for (int j = 0; j < 4; ++j) acc[i][j] = (f32x4){0.f, 0.f, 0.f, 0.f};

    bf16x8 afA[10], afB[10];
    // preload step-0 wf fragments
#pragma unroll
    for (int i = 0; i < 10; ++i) {
        int fm = i % 5, ks = i / 5;
        size_t f = (size_t)((c.wv * 5 + fm) * 16 + ks) * 512;
        afA[i] = *reinterpret_cast<const bf16x8*>(&wf[f + c.lane * 8]);
    }
    // prologue: stage x tile 0 into buf 0
    {
        f32x4 a = *reinterpret_cast<const f32x4*>(&c.xb[(2 * c.cp) * 64 + c.c4]);
        f32x4 d = *reinterpret_cast<const f32x4*>(&c.xb[(2 * c.cp + 1) * 64 + c.c4]);
#pragma unroll
        for (int j = 0; j < 4; ++j) {
            unsigned int pk = (unsigned int)f2bf(a[j]) | ((unsigned int)f2bf(d[j]) << 16);
            *reinterpret_cast<unsigned int*>(&xt[0][(c.c4 + j) * LDW1 + 2 * c.cp]) = pk;
        }
    }
    __syncthreads();

    k1_step<0>(c, acc, afA, afB);
    k1_step<1>(c, acc, afB, afA);
    k1_step<2>(c, acc, afA, afB);
    k1_step<3>(c, acc, afB, afA);
    k1_step<4>(c, acc, afA, afB);
    k1_step<5>(c, acc, afB, afA);
    k1_step<6>(c, acc, afA, afB);
    k1_step<7>(c, acc, afB, afA);

    // epilogue: BN1 (+folded BN3 for v) and scatter
    const int lane = c.lane, wv = c.wv, lm = c.lm, lg = c.lg;
    (void)lane;
#pragma unroll
    for (int fm = 0; fm < 5; ++fm) {
#pragma unroll
        for (int fn = 0; fn < 4; ++fn) {
            int d = fn * 16 + lm;
#pragma unroll
            for (int r = 0; r < 4; ++r) {
                int o = wv * 80 + fm * 16 + lg * 4 + r;
                int cc = o >> 3, hh = o & 7;
                float val = acc[fm][fn][r] * ssc[o] + ssh[o];
                unsigned short bv = f2bf(val);
                if (cc < 8)
                    qkA[(((size_t)b * 8 + hh) * 4 + (d >> 4)) * 512 + (d & 15) * 8 + cc] = bv;
                else if (cc < 16)
                    qkA[(((size_t)b * 8 + hh) * 4 + (d >> 4)) * 512 + ((d & 15) + 16) * 8 + (cc - 8)] = bv;
                else
                    vB[((size_t)(b * 8 + hh) * 64 + (cc - 16)) * 64 + d] = bv;
            }
        }
    }
    // zero qkA lanes 32..63 (MFMA upper-K zeros): 8 hh x 4 mf x 128 u32
    for (int z = tid; z < 4096; z += 512) {
        int hh  = z >> 9;
        int mf  = (z >> 7) & 3;
        int off = z & 127;
        unsigned int* p = reinterpret_cast<unsigned int*>(
            qkA + (((size_t)b * 8 + hh) * 4 + mf) * 512 + 256);
        p[off] = 0u;
    }
}

// ---------------------------------------------------------------------------
// K2: unchanged (validated).
// ---------------------------------------------------------------------------
#define SGP 84    // SGb row stride (f32)
#define SA  72    // attn row stride (u16)
#define RLD 136   // A2 row stride (u16)

__global__ __launch_bounds__(256) void k2_attn(
    const unsigned short* __restrict__ qkA, const unsigned short* __restrict__ vB,
    const unsigned short* __restrict__ relB, const unsigned short* __restrict__ relvA,
    const float* __restrict__ g2, const float* __restrict__ v2,
    const float* __restrict__ g3, const float* __restrict__ b3,
    const float* __restrict__ m3, const float* __restrict__ v3,
    float* __restrict__ outp)
{
    __shared__ float          SGb[64 * SGP];   // 21504 B
    __shared__ unsigned short attn[64 * SA];   // 9216 B
    __shared__ unsigned short A2[64 * RLD];    // 17408 B
    __shared__ float sh3[64];

    const int tid  = threadIdx.x;
    const int b    = blockIdx.x >> 3;
    const int h    = blockIdx.x & 7;
    const int lane = tid & 63;
    const int w    = tid >> 6;
    const int lmm  = lane & 15;
    const int lg   = lane >> 4;

    const unsigned short* qbase = qkA + ((size_t)(b * 8 + h) * 4) * 512;

    for (int i = tid; i < 64 * RLD / 2; i += 256)
        reinterpret_cast<unsigned int*>(A2)[i] = 0u;
    if (tid < 64) {
        int c = h * 64 + tid;
        float sa = g3[c] * rsqrtf(v3[c] + EPS_);
        float sb = g3[512 + c] * rsqrtf(v3[512 + c] + EPS_);
        sh3[tid] = (b3[c] - m3[c] * sa) + (b3[512 + c] - m3[512 + c] * sb);
    }
    const float s_dt = g2[3 * h + 2] * rsqrtf(v2[3 * h + 2] + EPS_);

    // ---- phase 1: MFMA scores ----
    bf16x8 aA = *reinterpret_cast<const bf16x8*>(&qbase[w * 512 + lane * 8]);
    bf16x8 zv = {0, 0, 0, 0, 0, 0, 0, 0};
    bf16x8 kBf[4];
#pragma unroll
    for (int jf = 0; jf < 4; ++jf) {
        kBf[jf] = zv;
        if (lane < 16)
            kBf[jf] = *reinterpret_cast<const bf16x8*>(&qbase[jf * 512 + (lane + 16) * 8]);
    }
    bf16x8 rBf[8];
#pragma unroll
    for (int uf = 0; uf < 8; ++uf)
        rBf[uf] = *reinterpret_cast<const bf16x8*>(&relB[(size_t)(h * 8 + uf) * 512 + lane * 8]);

    f32x4 dotsAcc[4];
#pragma unroll
    for (int jf = 0; jf < 4; ++jf)
        dotsAcc[jf] = __builtin_amdgcn_mfma_f32_16x16x32_bf16(
            aA, kBf[jf], (f32x4){0.f, 0.f, 0.f, 0.f}, 0, 0, 0);
    f32x4 sgAcc[8];
#pragma unroll
    for (int uf = 0; uf < 8; ++uf)
        sgAcc[uf] = __builtin_amdgcn_mfma_f32_16x16x32_bf16(
            aA, rBf[uf], (f32x4){0.f, 0.f, 0.f, 0.f}, 0, 0, 0);

    // write SGb (f32 band): row d = w*16 + lg*4 + r, t = u - d + 15
#pragma unroll
    for (int uf = 0; uf < 8; ++uf) {
#pragma unroll
        for (int r = 0; r < 4; ++r) {
            int d = (w << 4) + (lg << 2) + r;
            int t = uf * 16 + lmm - d + 15;
            if (t >= 0 && t < 79)
                SGb[d * SGP + t] = sgAcc[uf][r];
        }
    }
    __syncthreads();

    // ---- phase 2: softmax (row d across 16 lanes of the lg-group) ----
#pragma unroll
    for (int r = 0; r < 4; ++r) {
        int d = (w << 4) + (lg << 2) + r;
        const float* sgr = &SGb[d * SGP];
        float sc0 = s_dt * dotsAcc[0][r] + sgr[78 - lmm];
        float sc1 = s_dt * dotsAcc[1][r] + sgr[62 - lmm];
        float sc2 = s_dt * dotsAcc[2][r] + sgr[46 - lmm];
        float sc3 = s_dt * dotsAcc[3][r] + sgr[30 - lmm];
        float mx = fmaxf(fmaxf(sc0, sc1), fmaxf(sc2, sc3));
        mx = fmaxf(mx, __shfl_xor(mx, 1));
        mx = fmaxf(mx, __shfl_xor(mx, 2));
        mx = fmaxf(mx, __shfl_xor(mx, 4));
        mx = fmaxf(mx, __shfl_xor(mx, 8));
        float e0 = __expf(sc0 - mx), e1 = __expf(sc1 - mx);
        float e2 = __expf(sc2 - mx), e3 = __expf(sc3 - mx);
        float sum = (e0 + e1) + (e2 + e3);
        sum += __shfl_xor(sum, 1);
        sum += __shfl_xor(sum, 2);
        sum += __shfl_xor(sum, 4);
        sum += __shfl_xor(sum, 8);
        float inv = 1.f / sum;
        unsigned short p0 = f2bf(e0 * inv), p1 = f2bf(e1 * inv);
        unsigned short p2 = f2bf(e2 * inv), p3 = f2bf(e3 * inv);
        attn[d * SA + lmm]      = p0;
        attn[d * SA + 16 + lmm] = p1;
        attn[d * SA + 32 + lmm] = p2;
        attn[d * SA + 48 + lmm] = p3;
        A2[d * RLD + 63 + d - lmm] = p0;
        A2[d * RLD + 47 + d - lmm] = p1;
        A2[d * RLD + 31 + d - lmm] = p2;
        A2[d * RLD + 15 + d - lmm] = p3;
    }

    // ---- phase-3 A-fragment loads (global; land during barrier) ----
    const int lk8  = lg * 8;
    const int irow = (w << 4) + lmm;
    const unsigned short* vbase = vB + (size_t)(b * 8 + h) * 4096;
    bf16x8 av0 = *reinterpret_cast<const bf16x8*>(&vbase[irow * 64 + lk8]);
    bf16x8 av1 = *reinterpret_cast<const bf16x8*>(&vbase[irow * 64 + 32 + lk8]);
    bf16x8 rvA[4];
#pragma unroll
    for (int t = 0; t < 4; ++t)
        rvA[t] = *reinterpret_cast<const bf16x8*>(
            &relvA[(size_t)(((h * 4 + w) * 4 + t)) * 512 + lane * 8]);

    __syncthreads();

    // ---- phase 3: MFMA out + kv ----
    f32x4 acc[4];
#pragma unroll
    for (int nf = 0; nf < 4; ++nf) acc[nf] = (f32x4){0.f, 0.f, 0.f, 0.f};

#pragma unroll
    for (int nf = 0; nf < 4; ++nf) {
        const unsigned short* arow = &attn[(nf * 16 + lmm) * SA + lk8];
        acc[nf] = __builtin_amdgcn_mfma_f32_16x16x32_bf16(
            av0, *reinterpret_cast<const bf16x8*>(&arow[0]), acc[nf], 0, 0, 0);
        acc[nf] = __builtin_amdgcn_mfma_f32_16x16x32_bf16(
            av1, *reinterpret_cast<const bf16x8*>(&arow[32]), acc[nf], 0, 0, 0);
        const unsigned short* a2row = &A2[(nf * 16 + lmm) * RLD + lk8];
        acc[nf] = __builtin_amdgcn_mfma_f32_16x16x32_bf16(
            rvA[0], *reinterpret_cast<const bf16x8*>(&a2row[0]), acc[nf], 0, 0, 0);
        acc[nf] = __builtin_amdgcn_mfma_f32_16x16x32_bf16(
            rvA[1], *reinterpret_cast<const bf16x8*>(&a2row[32]), acc[nf], 0, 0, 0);
        acc[nf] = __builtin_amdgcn_mfma_f32_16x16x32_bf16(
            rvA[2], *reinterpret_cast<const bf16x8*>(&a2row[64]), acc[nf], 0, 0, 0);
        acc[nf] = __builtin_amdgcn_mfma_f32_16x16x32_bf16(
            rvA[3], *reinterpret_cast<const bf16x8*>(&a2row[96]), acc[nf], 0, 0, 0);
    }

    // ---- epilogue ----
    float* op = outp + ((size_t)b * 512 + h * 64) * 64;
    const int r0 = lg * 4;
#pragma unroll
    for (int r = 0; r < 4; ++r) {
        int i = (w << 4) + r0 + r;
        float sh = sh3[i];
#pragma unroll
        for (int nf = 0; nf < 4; ++nf)
            op[(size_t)i * 64 + nf * 16 + lmm] = acc[nf][r] + sh;
    }
}

extern "C" void kernel_launch(void* const* d_in, const int* in_sizes, int n_in,
                              void* d_out, int out_size, void* d_ws, size_t ws_size,
                              hipStream_t stream) {
    (void)in_sizes; (void)n_in; (void)out_size; (void)ws_size;
    const float* x   = (const float*)d_in[0];
    const float* w   = (const float*)d_in[1];
    const float* g1  = (const float*)d_in[2];
    const float* b1  = (const float*)d_in[3];
    const float* m1  = (const float*)d_in[4];
    const float* v1  = (const float*)d_in[5];
    const float* rel = (const float*)d_in[6];
    const float* g2  = (const float*)d_in[7];
    const float* b2  = (const float*)d_in[8];  (void)b2;
    const float* m2  = (const float*)d_in[9];  (void)m2;
    const float* v2  = (const float*)d_in[10];
    const float* g3  = (const float*)d_in[11];
    const float* b3  = (const float*)d_in[12];
    const float* m3  = (const float*)d_in[13];
    const float* v3  = (const float*)d_in[14];
    float* out = (float*)d_out;

    // ws: wf 640KB | relB 64KB | relvA 128KB | pad | qkA 32MB | vB 64MB
    unsigned short* wfrag = (unsigned short*)d_ws;
    unsigned short* relB  = (unsigned short*)((char*)d_ws + 655360);
    unsigned short* relvA = (unsigned short*)((char*)d_ws + 720896);
    unsigned short* qkA   = (unsigned short*)((char*)d_ws + 1048576);
    unsigned short* vB    = (unsigned short*)((char*)d_ws + 1048576 + (size_t)33554432);

    hipLaunchKernelGGL(k0_wconv, dim3(160), dim3(256), 0, stream, w, wfrag);
    hipLaunchKernelGGL(k0_tables, dim3(48), dim3(256), 0, stream,
                       rel, g2, v2, g3, v3, relB, relvA);
    hipLaunchKernelGGL(k1_gemm, dim3(1024), dim3(512), 0, stream,
                       x, wfrag, g1, b1, m1, v1, g3, v3, qkA, vB);
    hipLaunchKernelGGL(k2_attn, dim3(8192), dim3(256), 0, stream,
                       qkA, vB, relB, relvA, g2, v2, g3, b3, m3, v3, out);
}